// Round 3
// baseline (3927.643 us; speedup 1.0000x reference)
//
#include <hip/hip_runtime.h>
#include <hip/hip_bf16.h>

typedef __hip_bfloat16 bf16;

__device__ __forceinline__ float us2f(unsigned short u){ return __uint_as_float(((unsigned)u)<<16); }
__device__ __forceinline__ float sigf(float x){ return 1.0f/(1.0f+expf(-x)); }
__device__ __forceinline__ int clampi(int v, int lo, int hi){ return v<lo?lo:(v>hi?hi:v); }

// ---- float dtype detection: even ushort positions of a N(0,1) array are sane bf16 values
// iff the buffer really is bf16; if it is f32 they are random low mantissa halves.
__global__ void k_detect(const unsigned short* __restrict__ rn, int* __restrict__ mode)
{
    int tid = threadIdx.x;                 // 64 threads
    unsigned short u = rn[2*tid];
    int e = (u >> 7) & 0xFF;
    int sane = (u == 0) || (e >= 100 && e <= 140);
    unsigned long long m = __ballot(sane);
    if (tid == 0) mode[0] = (__popcll(m) >= 48) ? 1 : 0;   // 1 = bf16 buffers
}

// ---- float conversion: dst(f32) <- src interpreted per detected mode
__global__ void k_cvtf(const void* __restrict__ src, float* __restrict__ dst, int n,
                       const int* __restrict__ mode)
{
    int i = blockIdx.x*blockDim.x + threadIdx.x;
    if (i >= n) return;
    if (mode[0]) dst[i] = us2f(((const unsigned short*)src)[i]);
    else         dst[i] = ((const float*)src)[i];
}

// ---- int64/int32 tolerant index conversion (det = raw index_devices as int32; det[1]==0 <=> int64)
__global__ void k_cvt(const int* __restrict__ src, int* __restrict__ dst, int n,
                      const int* __restrict__ det)
{
    int i = blockIdx.x*blockDim.x + threadIdx.x;
    if (i >= n) return;
    int stride = (det[1] == 0) ? 2 : 1;
    dst[i] = src[(size_t)i*stride];
}

// ---------------- init projections: out[i,:] = X[src(i),0:5] @ W[5,128] + b ----------------
__global__ void k_proj5(const float* __restrict__ X, const float* __restrict__ W,
                        const float* __restrict__ bias,
                        const int* __restrict__ gidx, const int* __restrict__ sidx,
                        float* __restrict__ out, float* __restrict__ out2, int M, int nrows, int nodes)
{
    int t = blockIdx.x*blockDim.x + threadIdx.x;
    int i = t >> 7, j = t & 127;
    if (i >= M) return;
    int src = gidx ? clampi(gidx[i]-1, 0, nrows-1) : i;
    const float* xp = X + (size_t)src*5;
    float acc = bias[j];
#pragma unroll
    for (int k=0;k<5;k++) acc += xp[k] * W[k*128+j];
    int dr = sidx ? clampi(sidx[i], 0, nodes-1) : i;
    out[(size_t)dr*128 + j] = acc;
    if (out2) out2[(size_t)i*128 + j] = acc;
}

// ---------------- tiled GEMM: C[M,N] = prev(opt) + scale*(A[M,K]@B[K,N] + bias), all f32
// requires M%64==0, N%64==0, K%16==0
__launch_bounds__(256)
__global__ void k_gemm(const float* __restrict__ A, int lda,
                       const float* __restrict__ B, int ldb,
                       const float* __restrict__ bias, float* __restrict__ C,
                       int M, int N, int K, int relu, float scale, int accum)
{
    __shared__ float As[16][65];
    __shared__ float Bs[16][65];
    int tid = threadIdx.x;
    int tx = tid & 15, ty = tid >> 4;
    int row0 = blockIdx.y*64, col0 = blockIdx.x*64;
    int ra = tid >> 2, ka = (tid & 3)*4;
    int rb = tid >> 4, cb = (tid & 15)*4;
    float acc[4][4] = {};
    for (int k0=0;k0<K;k0+=16){
        float4 av = *reinterpret_cast<const float4*>(A + (size_t)(row0+ra)*lda + k0 + ka);
        float4 bv = *reinterpret_cast<const float4*>(B + (size_t)(k0+rb)*ldb + col0 + cb);
        As[ka+0][ra]=av.x; As[ka+1][ra]=av.y; As[ka+2][ra]=av.z; As[ka+3][ra]=av.w;
        Bs[rb][cb+0]=bv.x; Bs[rb][cb+1]=bv.y; Bs[rb][cb+2]=bv.z; Bs[rb][cb+3]=bv.w;
        __syncthreads();
#pragma unroll
        for (int k=0;k<16;k++){
            float a0=As[k][ty*4+0],a1=As[k][ty*4+1],a2=As[k][ty*4+2],a3=As[k][ty*4+3];
            float b0=Bs[k][tx*4+0],b1=Bs[k][tx*4+1],b2=Bs[k][tx*4+2],b3=Bs[k][tx*4+3];
            acc[0][0]+=a0*b0; acc[0][1]+=a0*b1; acc[0][2]+=a0*b2; acc[0][3]+=a0*b3;
            acc[1][0]+=a1*b0; acc[1][1]+=a1*b1; acc[1][2]+=a1*b2; acc[1][3]+=a1*b3;
            acc[2][0]+=a2*b0; acc[2][1]+=a2*b1; acc[2][2]+=a2*b2; acc[2][3]+=a2*b3;
            acc[3][0]+=a3*b0; acc[3][1]+=a3*b1; acc[3][2]+=a3*b2; acc[3][3]+=a3*b3;
        }
        __syncthreads();
    }
    float bb[4];
#pragma unroll
    for (int j=0;j<4;j++) bb[j] = bias ? bias[col0+tx*4+j] : 0.f;
#pragma unroll
    for (int i=0;i<4;i++){
        float* cp = C + (size_t)(row0+ty*4+i)*N + col0 + tx*4;
        float4 prev = accum ? *reinterpret_cast<const float4*>(cp) : make_float4(0,0,0,0);
        float v[4];
#pragma unroll
        for (int j=0;j<4;j++){
            float u = acc[i][j] + bb[j];
            if (relu) u = fmaxf(u, 0.f);
            v[j] = u;
        }
        float4 o;
        o.x = prev.x + scale*v[0]; o.y = prev.y + scale*v[1];
        o.z = prev.z + scale*v[2]; o.w = prev.w + scale*v[3];
        *reinterpret_cast<float4*>(cp) = o;
    }
}

// ---------------- GRU pointwise (gate order r,z,n). Optional length-mask + out_f scatter.
__global__ void k_gru(const float* __restrict__ gi, const float* __restrict__ gh,
                      const float* __restrict__ hin, float* __restrict__ hout,
                      float* __restrict__ out_f, const int* __restrict__ inv,
                      const int* __restrict__ lengths, int t, int L, int M, int F)
{
    int idx = blockIdx.x*blockDim.x + threadIdx.x;
    int i = idx >> 7, j = idx & 127;
    if (i >= M) return;
    size_t g = (size_t)i*384;
    float r = sigf(gi[g+j]     + gh[g+j]);
    float z = sigf(gi[g+128+j] + gh[g+128+j]);
    float n = tanhf(gi[g+256+j] + r*gh[g+256+j]);
    float hv = hin[(size_t)i*128+j];
    float hn = (1.f-z)*n + z*hv;
    if (lengths && t >= lengths[i]) hn = hv;
    hout[(size_t)i*128+j] = hn;
    if (inv){ int f = inv[i*L+t]; if (f >= 0 && f < F) out_f[(size_t)f*128+j] = hn; }
}

// ---------------- gather seq row for phiC step t
__global__ void k_gather_seq(const float* __restrict__ state, const int* __restrict__ exe,
                             float* __restrict__ xcat, int S, int L, int t, int nodes)
{
    int idx = blockIdx.x*blockDim.x + threadIdx.x;
    int s = idx >> 8, j = idx & 255;
    if (s >= S) return;
    int node = clampi(exe[(size_t)s*2*L + 2*t + (j>>7)], 0, nodes-1);
    xcat[(size_t)s*256 + j] = state[(size_t)node*128 + (j&127)];
}

// ---------------- concat: out[i,:] = [A128[i], (gidx? state[gidx[i]] : B128[i])]
__global__ void k_concat(const float* __restrict__ A128, const float* __restrict__ B128,
                         const float* __restrict__ state, const int* __restrict__ gidx,
                         float* __restrict__ outv, int M, int nodes)
{
    int idx = blockIdx.x*blockDim.x + threadIdx.x;
    int i = idx >> 8, j = idx & 255;
    if (i >= M) return;
    float v;
    if (j < 128) v = A128[(size_t)i*128 + j];
    else        v = gidx ? state[(size_t)clampi(gidx[i],0,nodes-1)*128 + (j-128)]
                         : B128[(size_t)i*128 + (j-128)];
    outv[(size_t)i*256 + j] = v;
}

// ---------------- fused alpha: alpha[f,h] = sum_c lrelu((xcat@Wsrc)[f,h,c]+bsrc+tgt[row,h,c])*att
__launch_bounds__(256)
__global__ void k_alpha_fused(const float* __restrict__ A, const float* __restrict__ tgt,
                              const int* __restrict__ rowid, const float* __restrict__ W,
                              const float* __restrict__ bsrc, const float* __restrict__ att,
                              float* __restrict__ alpha, int F, int Dn)
{
    __shared__ float As[16][65];
    __shared__ float Bs[16][65];
    __shared__ int rows[64];
    __shared__ float red[64][17];
    int tid = threadIdx.x;
    int tx = tid & 15, ty = tid >> 4;
    int h = blockIdx.x;
    int row0 = blockIdx.y * 64;
    if (tid < 64) rows[tid] = clampi(rowid[row0 + tid], 0, Dn-1);
    int ra = tid >> 2, ka = (tid & 3)*4;
    int rb = tid >> 4, cb = (tid & 15)*4;
    float rowsum[4] = {0,0,0,0};
    for (int ct=0; ct<4; ++ct){
        int colbase = h*256 + ct*64;
        float acc[4][4] = {};
        for (int k0=0;k0<256;k0+=16){
            __syncthreads();
            float4 av = *reinterpret_cast<const float4*>(A + (size_t)(row0+ra)*256 + k0 + ka);
            float4 bv = *reinterpret_cast<const float4*>(W + (size_t)(k0+rb)*1024 + colbase + cb);
            As[ka+0][ra]=av.x; As[ka+1][ra]=av.y; As[ka+2][ra]=av.z; As[ka+3][ra]=av.w;
            Bs[rb][cb+0]=bv.x; Bs[rb][cb+1]=bv.y; Bs[rb][cb+2]=bv.z; Bs[rb][cb+3]=bv.w;
            __syncthreads();
#pragma unroll
            for (int k=0;k<16;k++){
                float a0=As[k][ty*4+0],a1=As[k][ty*4+1],a2=As[k][ty*4+2],a3=As[k][ty*4+3];
                float b0=Bs[k][tx*4+0],b1=Bs[k][tx*4+1],b2=Bs[k][tx*4+2],b3=Bs[k][tx*4+3];
                acc[0][0]+=a0*b0; acc[0][1]+=a0*b1; acc[0][2]+=a0*b2; acc[0][3]+=a0*b3;
                acc[1][0]+=a1*b0; acc[1][1]+=a1*b1; acc[1][2]+=a1*b2; acc[1][3]+=a1*b3;
                acc[2][0]+=a2*b0; acc[2][1]+=a2*b1; acc[2][2]+=a2*b2; acc[2][3]+=a2*b3;
                acc[3][0]+=a3*b0; acc[3][1]+=a3*b1; acc[3][2]+=a3*b2; acc[3][3]+=a3*b3;
            }
        }
#pragma unroll
        for (int i=0;i<4;i++){
            const float* tp = tgt + (size_t)rows[ty*4+i]*1024 + colbase + tx*4;
            float4 tv = *reinterpret_cast<const float4*>(tp);
            float t4[4] = {tv.x, tv.y, tv.z, tv.w};
#pragma unroll
            for (int j=0;j<4;j++){
                int c = colbase + tx*4 + j;
                float e = acc[i][j] + bsrc[c] + t4[j];
                e = e > 0.f ? e : 0.2f*e;
                rowsum[i] += e * att[c];
            }
        }
    }
#pragma unroll
    for (int i=0;i<4;i++) red[ty*4+i][tx] = rowsum[i];
    __syncthreads();
    if (tid < 64){
        float s = 0.f;
#pragma unroll
        for (int x=0;x<16;x++) s += red[tid][x];
        alpha[(size_t)(row0+tid)*4 + h] = s;
    }
}

// ---------------- per-device softmax + weighted xcat sum: z[d,h,:] = sum a*xcat[f,:]; sa[d,h]=sum a
__global__ void k_attn_z(const float* __restrict__ xcat, const float* __restrict__ alpha,
                         const int* __restrict__ list, const int* __restrict__ offs,
                         float* __restrict__ z, float* __restrict__ sa, int Dn, int F)
{
    int d = blockIdx.x;
    int tid = threadIdx.x;
    int h = tid >> 6, lane = tid & 63;
    int beg = offs[d], end = offs[d+1];
    if (beg < 0) beg = 0; if (end > F) end = F; if (end < beg) end = beg;
    float amax = -3.4e38f;
    for (int i=beg;i<end;i++) amax = fmaxf(amax, alpha[(size_t)list[i]*4+h]);
    float wsum = 0.f;
    for (int i=beg;i<end;i++) wsum += expf(alpha[(size_t)list[i]*4+h]-amax);
    float iws = 1.f/(wsum + 1e-16f);
    float acc[4] = {0,0,0,0};
    for (int i=beg;i<end;i++){
        int f = list[i];
        float a = expf(alpha[(size_t)f*4+h]-amax)*iws;
        const float* xp = xcat + (size_t)f*256;
#pragma unroll
        for (int q=0;q<4;q++) acc[q] += a * xp[lane + q*64];
    }
#pragma unroll
    for (int q=0;q<4;q++) z[(size_t)d*1024 + h*256 + lane + q*64] = acc[q];
    if (lane == 0) sa[d*4+h] = (end>beg) ? wsum*iws : 0.f;
}

// ---------------- msgD correction: += bias_att + 0.25*sum_h sa[d,h]*b_src[h*256+c]
__global__ void k_msgd_fix(float* __restrict__ msgD, const float* __restrict__ sa,
                           const float* __restrict__ bsrc, const float* __restrict__ batt, int Dn)
{
    int idx = blockIdx.x*blockDim.x + threadIdx.x;
    int d = idx >> 8, c = idx & 255;
    if (d >= Dn) return;
    float v = batt[c];
#pragma unroll
    for (int h=0;h<4;h++) v += 0.25f * sa[d*4+h] * bsrc[h*256+c];
    msgD[(size_t)d*256 + c] += v;
}

// ---------------- scatter 128-wide rows into state by node index
__global__ void k_scatter(const float* __restrict__ buf, const int* __restrict__ idx,
                          float* __restrict__ state, int M, int nodes)
{
    int t = blockIdx.x*blockDim.x + threadIdx.x;
    int i = t >> 7, j = t & 127;
    if (i >= M) return;
    state[(size_t)clampi(idx[i],0,nodes-1)*128 + j] = buf[(size_t)i*128 + j];
}

// ---------------- device fragment list build (counting sort) ----------------
__global__ void k_count(const int* __restrict__ row, int* __restrict__ counts, int F, int Dn)
{ int f = blockIdx.x*blockDim.x + threadIdx.x; if (f < F) atomicAdd(&counts[clampi(row[f],0,Dn-1)], 1); }

__global__ void k_scan(const int* __restrict__ counts, int* __restrict__ offs, int D)
{
    __shared__ int part[257];
    int tid = threadIdx.x;
    int per = (D + 255) / 256;
    int s = 0;
    for (int i=0;i<per;i++){ int idx = tid*per+i; if (idx < D) s += counts[idx]; }
    part[tid] = s;
    __syncthreads();
    if (tid == 0){
        int acc = 0;
        for (int i=0;i<256;i++){ int v = part[i]; part[i] = acc; acc += v; }
        part[256] = acc;
    }
    __syncthreads();
    int acc = part[tid];
    for (int i=0;i<per;i++){ int idx = tid*per+i; if (idx < D){ offs[idx] = acc; acc += counts[idx]; } }
    if (tid == 0) offs[D] = part[256];
}

__global__ void k_fill(const int* __restrict__ row, const int* __restrict__ offs,
                       int* __restrict__ cursor, int* __restrict__ list, int F, int Dn)
{
    int f = blockIdx.x*blockDim.x + threadIdx.x;
    if (f >= F) return;
    int r = clampi(row[f],0,Dn-1);
    int p = atomicAdd(&cursor[r], 1);
    int pos = offs[r]+p;
    if (pos >= 0 && pos < F) list[pos] = f;
}

__global__ void k_build_inv(const int* __restrict__ fs, const int* __restrict__ fp,
                            int* __restrict__ inv, int F, int L, int S)
{
    int f = blockIdx.x*blockDim.x + threadIdx.x;
    if (f >= F) return;
    inv[clampi(fs[f],0,S-1)*L + clampi(fp[f],0,L-1)] = f;
}

// ---------------- pooling + readout ----------------
__global__ void k_pool_add(const float* __restrict__ frag, const int* __restrict__ fs,
                           float* __restrict__ pooled, int F, int S)
{
    int t = blockIdx.x*blockDim.x + threadIdx.x;
    int i = t >> 7, j = t & 127;
    if (i >= F) return;
    atomicAdd(&pooled[(size_t)clampi(fs[i],0,S-1)*128 + j], frag[(size_t)i*128 + j]);
}

__global__ void k_pool_div(float* __restrict__ pooled, const int* __restrict__ lengths, int S)
{
    int t = blockIdx.x*blockDim.x + threadIdx.x;
    int i = t >> 7, j = t & 127;
    if (i >= S) return;
    int l = lengths[i]; if (l < 1) l = 1;
    pooled[(size_t)i*128 + j] /= (float)l;
}

__global__ void k_dot_out(const float* __restrict__ H, const float* __restrict__ W3,
                          const float* __restrict__ b3, void* __restrict__ outv, int off,
                          const int* __restrict__ mode)
{
    __shared__ float red[256];
    int s = blockIdx.x, tid = threadIdx.x;
    red[tid] = H[(size_t)s*256 + tid] * W3[tid];
    __syncthreads();
    for (int st=128; st; st>>=1){ if (tid < st) red[tid] += red[tid+st]; __syncthreads(); }
    if (tid == 0){
        float v = red[0] + b3[0];
        if (mode[0]) ((bf16*)outv)[off + s] = __float2bfloat16(v);
        else         ((float*)outv)[off + s] = v;
    }
}

// =====================================================================================
extern "C" void kernel_launch(void* const* d_in, const int* in_sizes, int n_in,
                              void* d_out, int out_size, void* d_ws, size_t ws_size,
                              hipStream_t stream)
{
    (void)n_in; (void)out_size; (void)ws_size;
    const int* r_exe   = (const int*)d_in[2];
    const int* r_idev  = (const int*)d_in[3];
    const int* r_ifrag = (const int*)d_in[4];
    const int* r_fdn   = (const int*)d_in[5];
    const int* r_fdr   = (const int*)d_in[6];
    const int* r_len   = (const int*)d_in[7];
    const int* r_fsvc  = (const int*)d_in[8];
    const int* r_fpos  = (const int*)d_in[9];

    const int S  = in_sizes[7];              // 2048
    const int Dn = in_sizes[3];              // 4096
    const int F  = in_sizes[4];              // 20480
    const int L  = in_sizes[2] / (2*S);      // 16
    const int nreal = in_sizes[0]/5;         // 24576
    const int nodes = nreal + 1;             // 24577
    const int NIT = 3;
    const int FH = F/2;                      // F-GRU chunk rows

    // ---- workspace arena ----
    char* wp = (char*)d_ws;
    auto alloc = [&](size_t nelem)->float*{
        float* p = (float*)wp;
        wp += ((nelem*4 + 255)/256)*256;
        return p;
    };
    float* state  = alloc((size_t)nodes*128);
    float* h_srv  = alloc((size_t)S*128);
    float* out_f  = alloc((size_t)F*128);
    float* fragA  = alloc((size_t)F*128);
    float* fragB  = alloc((size_t)F*128);
    float* devA   = alloc((size_t)Dn*128);
    float* devB   = alloc((size_t)Dn*128);
    float* alphaB = alloc((size_t)F*4);
    float* msgDm  = alloc((size_t)Dn*256);
    float* saB    = alloc((size_t)Dn*4);
    float* XC     = alloc((size_t)F*256);
    float* B1     = alloc((size_t)Dn*1024);
    float* B2     = alloc((size_t)Dn*1024);
    int* mode   = (int*)alloc(4);
    int* cExe   = (int*)alloc((size_t)S*2*L);
    int* cIdev  = (int*)alloc((size_t)Dn);
    int* cIfrag = (int*)alloc((size_t)F);
    int* cFdn   = (int*)alloc((size_t)F);
    int* cFdr   = (int*)alloc((size_t)F);
    int* cLen   = (int*)alloc((size_t)S);
    int* cFsvc  = (int*)alloc((size_t)F);
    int* cFpos  = (int*)alloc((size_t)F);
    int* inv    = (int*)alloc((size_t)S*L);
    int* counts = (int*)alloc((size_t)Dn);
    int* offs   = (int*)alloc((size_t)Dn+1);
    int* cursor = (int*)alloc((size_t)Dn);
    int* list   = (int*)alloc((size_t)F);

    // ---- float input conversion targets (all f32 in ws) ----
    struct CvtEnt { int idx; float* dst; int n; };
    float* wRN   = alloc((size_t)nreal*5);
    float* wARR  = alloc((size_t)S*5);
    float* wWdev = alloc(640);  float* wBdev = alloc(128);
    float* wWfrg = alloc(640);  float* wBfrg = alloc(128);
    float* wWsrv = alloc(640);  float* wBsrv = alloc(128);
    float* wCWih = alloc(256*384); float* wCWhh = alloc(128*384); float* wCbih = alloc(384); float* wCbhh = alloc(384);
    float* wFWih = alloc(256*384); float* wFWhh = alloc(128*384); float* wFbih = alloc(384); float* wFbhh = alloc(384);
    float* wDWih = alloc(256*384); float* wDWhh = alloc(128*384); float* wDbih = alloc(384); float* wDbhh = alloc(384);
    float* wWsrc = alloc(256*1024); float* wBsrc = alloc(1024);
    float* wWtgt = alloc(128*1024); float* wBtgt = alloc(1024);
    float* wAtt  = alloc(1024);     float* wBatt = alloc(256);
    float* wWt1 = alloc(128*256); float* wbt1 = alloc(256); float* wWt2 = alloc(256*256); float* wbt2 = alloc(256);
    float* wWt3 = alloc(256);     float* wbt3 = alloc(1);
    float* wWl1 = alloc(128*256); float* wbl1 = alloc(256); float* wWl2 = alloc(256*256); float* wbl2 = alloc(256);
    float* wWl3 = alloc(256);     float* wbl3 = alloc(1);

    // ---- detect float dtype, convert all float inputs to f32 ----
    k_detect<<<1,64,0,stream>>>((const unsigned short*)d_in[0], mode);
    CvtEnt ents[] = {
        {0,wRN,nreal*5},{1,wARR,S*5},
        {10,wWdev,640},{11,wBdev,128},{12,wWfrg,640},{13,wBfrg,128},{14,wWsrv,640},{15,wBsrv,128},
        {16,wCWih,256*384},{17,wCWhh,128*384},{18,wCbih,384},{19,wCbhh,384},
        {20,wFWih,256*384},{21,wFWhh,128*384},{22,wFbih,384},{23,wFbhh,384},
        {24,wDWih,256*384},{25,wDWhh,128*384},{26,wDbih,384},{27,wDbhh,384},
        {28,wWsrc,256*1024},{29,wBsrc,1024},{30,wWtgt,128*1024},{31,wBtgt,1024},
        {32,wAtt,1024},{33,wBatt,256},
        {34,wWt1,128*256},{35,wbt1,256},{36,wWt2,256*256},{37,wbt2,256},{38,wWt3,256},{39,wbt3,1},
        {40,wWl1,128*256},{41,wbl1,256},{42,wWl2,256*256},{43,wbl2,256},{44,wWl3,256},{45,wbl3,1},
    };
    for (auto& e : ents)
        k_cvtf<<<dim3((e.n+255)/256),256,0,stream>>>(d_in[e.idx], e.dst, e.n, mode);

    // ---- int width detection + conversion ----
    const int* det = r_idev;
    auto cvt = [&](const int* src, int* dst, int n){
        k_cvt<<<dim3((n+255)/256),256,0,stream>>>(src, dst, n, det);
    };
    cvt(r_exe,  cExe,  S*2*L);
    cvt(r_idev, cIdev, Dn);
    cvt(r_ifrag,cIfrag,F);
    cvt(r_fdn,  cFdn,  F);
    cvt(r_fdr,  cFdr,  F);
    cvt(r_len,  cLen,  S);
    cvt(r_fsvc, cFsvc, F);
    cvt(r_fpos, cFpos, F);

    hipMemsetAsync(state, 0, (size_t)nodes*128*4, stream);
    hipMemsetAsync(inv, 0xFF, (size_t)S*L*4, stream);
    hipMemsetAsync(counts, 0, (size_t)Dn*4, stream);
    hipMemsetAsync(cursor, 0, (size_t)Dn*4, stream);

    // init projections + index structures
    k_proj5<<<dim3((Dn*128+255)/256),256,0,stream>>>(wRN, wWdev, wBdev, cIdev, cIdev, state, devA, Dn, nreal, nodes);
    k_proj5<<<dim3(((size_t)F*128+255)/256),256,0,stream>>>(wRN, wWfrg, wBfrg, cIfrag, cIfrag, state, fragA, F, nreal, nodes);
    k_proj5<<<dim3((S*128+255)/256),256,0,stream>>>(wARR, wWsrv, wBsrv, nullptr, nullptr, h_srv, nullptr, S, S, nodes);
    k_build_inv<<<dim3((F+255)/256),256,0,stream>>>(cFsvc, cFpos, inv, F, L, S);
    k_count<<<dim3((F+255)/256),256,0,stream>>>(cFdr, counts, F, Dn);
    k_scan<<<1,256,0,stream>>>(counts, offs, Dn);
    k_fill<<<dim3((F+255)/256),256,0,stream>>>(cFdr, offs, cursor, list, F, Dn);

    float *fragCur=fragA, *fragNxt=fragB, *devCur=devA, *devNxt=devB;

    for (int it=0; it<NIT; ++it){
        // ---- phiC packed GRU (L sequential steps) ----
        for (int t=0;t<L;t++){
            k_gather_seq<<<dim3((S*256+255)/256),256,0,stream>>>(state, cExe, XC, S, L, t, nodes);
            k_gemm<<<dim3(384/64, S/64),256,0,stream>>>(XC, 256, wCWih, 384, wCbih, B1, S, 384, 256, 0, 1.f, 0);
            k_gemm<<<dim3(384/64, S/64),256,0,stream>>>(h_srv, 128, wCWhh, 384, wCbhh, B2, S, 384, 128, 0, 1.f, 0);
            k_gru<<<dim3((S*128+255)/256),256,0,stream>>>(B1, B2, h_srv, h_srv, out_f, inv, cLen, t, L, S, F);
        }
        // ---- attention ----
        k_concat<<<dim3(((size_t)F*256+255)/256),256,0,stream>>>(out_f, fragCur, nullptr, nullptr, XC, F, nodes);
        k_gemm<<<dim3(1024/64, Dn/64),256,0,stream>>>(devCur, 128, wWtgt, 1024, wBtgt, B1, Dn, 1024, 128, 0, 1.f, 0);
        k_alpha_fused<<<dim3(4, F/64),256,0,stream>>>(XC, B1, cFdr, wWsrc, wBsrc, wAtt, alphaB, F, Dn);
        k_attn_z<<<dim3(Dn),256,0,stream>>>(XC, alphaB, list, offs, B2, saB, Dn, F);
        for (int h=0;h<4;h++)
            k_gemm<<<dim3(256/64, Dn/64),256,0,stream>>>(B2 + h*256, 1024, wWsrc + h*256, 1024, nullptr, msgDm, Dn, 256, 256, 0, 0.25f, h>0);
        k_msgd_fix<<<dim3((Dn*256+255)/256),256,0,stream>>>(msgDm, saB, wBsrc, wBatt, Dn);
        // ---- F-GRU (msgF = [out_f | state[frag2dev_node]]), chunked 2x ----
        k_concat<<<dim3(((size_t)F*256+255)/256),256,0,stream>>>(out_f, nullptr, state, cFdn, XC, F, nodes);
        for (int c=0;c<2;c++){
            size_t off = (size_t)c*FH;
            k_gemm<<<dim3(384/64, FH/64),256,0,stream>>>(XC + off*256, 256, wFWih, 384, wFbih, B1, FH, 384, 256, 0, 1.f, 0);
            k_gemm<<<dim3(384/64, FH/64),256,0,stream>>>(fragCur + off*128, 128, wFWhh, 384, wFbhh, B2, FH, 384, 128, 0, 1.f, 0);
            k_gru<<<dim3(((size_t)FH*128+255)/256),256,0,stream>>>(B1, B2, fragCur + off*128, fragNxt + off*128, nullptr, nullptr, nullptr, 0, L, FH, F);
        }
        // ---- D-GRU ----
        k_gemm<<<dim3(384/64, Dn/64),256,0,stream>>>(msgDm, 256, wDWih, 384, wDbih, B1, Dn, 384, 256, 0, 1.f, 0);
        k_gemm<<<dim3(384/64, Dn/64),256,0,stream>>>(devCur, 128, wDWhh, 384, wDbhh, B2, Dn, 384, 128, 0, 1.f, 0);
        k_gru<<<dim3((Dn*128+255)/256),256,0,stream>>>(B1, B2, devCur, devNxt, nullptr, nullptr, nullptr, 0, L, Dn, F);
        // ---- scatter new states ----
        k_scatter<<<dim3(((size_t)F*128+255)/256),256,0,stream>>>(fragNxt, cIfrag, state, F, nodes);
        k_scatter<<<dim3((Dn*128+255)/256),256,0,stream>>>(devNxt, cIdev, state, Dn, nodes);
        float* tp;
        tp=fragCur; fragCur=fragNxt; fragNxt=tp;
        tp=devCur;  devCur=devNxt;  devNxt=tp;
    }

    // ---- readout ----
    float* pooled = XC;
    hipMemsetAsync(pooled, 0, (size_t)S*128*4, stream);
    k_pool_add<<<dim3(((size_t)F*128+255)/256),256,0,stream>>>(fragCur, cFsvc, pooled, F, S);
    k_pool_div<<<dim3((S*128+255)/256),256,0,stream>>>(pooled, cLen, S);
    // latency head (pooled)
    k_gemm<<<dim3(256/64, S/64),256,0,stream>>>(pooled, 128, wWl1, 256, wbl1, B1, S, 256, 128, 1, 1.f, 0);
    k_gemm<<<dim3(256/64, S/64),256,0,stream>>>(B1, 256, wWl2, 256, wbl2, B2, S, 256, 256, 1, 1.f, 0);
    k_dot_out<<<dim3(S),256,0,stream>>>(B2, wWl3, wbl3, d_out, 0, mode);
    // throughput head (h_srv)
    k_gemm<<<dim3(256/64, S/64),256,0,stream>>>(h_srv, 128, wWt1, 256, wbt1, B1, S, 256, 128, 1, 1.f, 0);
    k_gemm<<<dim3(256/64, S/64),256,0,stream>>>(B1, 256, wWt2, 256, wbt2, B2, S, 256, 256, 1, 1.f, 0);
    k_dot_out<<<dim3(S),256,0,stream>>>(B2, wWt3, wbt3, d_out, S, mode);
}

// Round 4
// 2748.550 us; speedup vs baseline: 1.4290x; 1.4290x over previous
//
#include <hip/hip_runtime.h>
#include <hip/hip_bf16.h>

__device__ __forceinline__ float sigf(float x){ return 1.0f/(1.0f+expf(-x)); }
__device__ __forceinline__ int clampi(int v, int lo, int hi){ return v<lo?lo:(v>hi?hi:v); }

// ---- int64/int32 tolerant index conversion (det = raw index_devices as int32; det[1]==0 <=> int64)
__global__ void k_cvt(const int* __restrict__ src, int* __restrict__ dst, int n,
                      const int* __restrict__ det)
{
    int i = blockIdx.x*blockDim.x + threadIdx.x;
    if (i >= n) return;
    int stride = (det[1] == 0) ? 2 : 1;
    dst[i] = src[(size_t)i*stride];
}

// ---------------- init projections: out[i,:] = X[src(i),0:5] @ W[5,128] + b ----------------
__global__ void k_proj5(const float* __restrict__ X, const float* __restrict__ W,
                        const float* __restrict__ bias,
                        const int* __restrict__ gidx, const int* __restrict__ sidx,
                        float* __restrict__ out, float* __restrict__ out2, int M, int nrows, int nodes)
{
    int t = blockIdx.x*blockDim.x + threadIdx.x;
    int i = t >> 7, j = t & 127;
    if (i >= M) return;
    int src = gidx ? clampi(gidx[i]-1, 0, nrows-1) : i;
    const float* xp = X + (size_t)src*5;
    float acc = bias[j];
#pragma unroll
    for (int k=0;k<5;k++) acc += xp[k] * W[k*128+j];
    int dr = sidx ? clampi(sidx[i], 0, nodes-1) : i;
    out[(size_t)dr*128 + j] = acc;
    if (out2) out2[(size_t)i*128 + j] = acc;
}

// ---------------- unified tiled GEMM, 128x128 tile, 8x8 micro-tile ----------------
// A modes: A1!=null -> two-half indexed A (row stride 128 each, K==256):
//            k<128: A0[idx0(r)*128+k], k>=128: A1[idx1(r)*128+k-128]; idx = i?[r] else r
//          A1==null -> linear A0 with leading dim lda.
// epi==0: C = (accum?C:0) + scale*(relu?max(0,AB+bias):AB+bias)
// epi==1: GAT alpha epilogue: e = AB + bsrc[c] + tgt[rowIdx[r]*1024+c]; lrelu(.2);
//         atomicAdd(alpha[r*4 + col0/256], sum_c e*att[c])
// Requires M%128==0, N%128==0, K%16==0.
__launch_bounds__(256)
__global__ void k_mm(const float* __restrict__ A0, const float* __restrict__ A1,
                     const int* __restrict__ i0, const int* __restrict__ i1, int lda,
                     const float* __restrict__ B, int ldb,
                     const float* __restrict__ bias, float* __restrict__ C,
                     int M, int N, int K, int relu, float scale, int accum,
                     int epi, const float* __restrict__ tgtP, const int* __restrict__ rowIdx,
                     const float* __restrict__ attP, const float* __restrict__ bsrcP,
                     float* __restrict__ alphaP)
{
    __shared__ float As[16][132];
    __shared__ float Bs[16][132];
    __shared__ float red[128][17];
    int tid = threadIdx.x;
    int tx = tid & 15, ty = tid >> 4;
    int row0 = blockIdx.y * 128, col0 = blockIdx.x * 128;
    float acc[8][8] = {};
    for (int k0 = 0; k0 < K; k0 += 16){
#pragma unroll
        for (int q = 0; q < 2; ++q){
            int idx = tid + q*256;
            int r = idx >> 2, k4 = (idx & 3) * 4;
            int kk = k0 + k4;
            const float* src;
            if (A1){
                if (kk < 128){ int ri = i0 ? i0[row0+r] : (row0+r); src = A0 + (size_t)ri*128 + kk; }
                else         { int ri = i1 ? i1[row0+r] : (row0+r); src = A1 + (size_t)ri*128 + (kk-128); }
            } else {
                src = A0 + (size_t)(row0+r)*lda + kk;
            }
            float4 v = *reinterpret_cast<const float4*>(src);
            As[k4+0][r]=v.x; As[k4+1][r]=v.y; As[k4+2][r]=v.z; As[k4+3][r]=v.w;
        }
#pragma unroll
        for (int q = 0; q < 2; ++q){
            int idx = tid + q*256;
            int kb = idx >> 5, n4 = (idx & 31) * 4;
            float4 v = *reinterpret_cast<const float4*>(B + (size_t)(k0+kb)*ldb + col0 + n4);
            *reinterpret_cast<float4*>(&Bs[kb][n4]) = v;
        }
        __syncthreads();
#pragma unroll
        for (int k = 0; k < 16; ++k){
            float a[8], b[8];
            *(float4*)&a[0] = *(const float4*)&As[k][ty*8];
            *(float4*)&a[4] = *(const float4*)&As[k][ty*8+4];
            *(float4*)&b[0] = *(const float4*)&Bs[k][tx*8];
            *(float4*)&b[4] = *(const float4*)&Bs[k][tx*8+4];
#pragma unroll
            for (int i=0;i<8;i++)
#pragma unroll
                for (int j=0;j<8;j++) acc[i][j] += a[i]*b[j];
        }
        __syncthreads();
    }
    if (epi == 0){
        float bb[8];
#pragma unroll
        for (int j=0;j<8;j++) bb[j] = bias ? bias[col0+tx*8+j] : 0.f;
#pragma unroll
        for (int i=0;i<8;i++){
            float* cp = C + (size_t)(row0+ty*8+i)*N + col0 + tx*8;
#pragma unroll
            for (int jq=0;jq<2;jq++){
                float4 prev = accum ? *(const float4*)(cp+jq*4) : make_float4(0,0,0,0);
                float o[4];
#pragma unroll
                for (int c=0;c<4;c++){
                    float u = acc[i][jq*4+c] + bb[jq*4+c];
                    if (relu) u = fmaxf(u,0.f);
                    o[c] = (&prev.x)[c] + scale*u;
                }
                *(float4*)(cp+jq*4) = make_float4(o[0],o[1],o[2],o[3]);
            }
        }
    } else {
        int h = col0 >> 8;
        float ps[8];
#pragma unroll
        for (int i=0;i<8;i++){
            int r = row0 + ty*8 + i;
            int dr = rowIdx[r];
            const float* tp = tgtP + (size_t)dr*1024 + col0 + tx*8;
            float s = 0.f;
#pragma unroll
            for (int j=0;j<8;j++){
                int c = col0 + tx*8 + j;
                float e = acc[i][j] + bsrcP[c] + tp[j];
                e = e > 0.f ? e : 0.2f*e;
                s += e * attP[c];
            }
            ps[i] = s;
        }
#pragma unroll
        for (int i=0;i<8;i++) red[ty*8+i][tx] = ps[i];
        __syncthreads();
        if (tid < 128){
            float s = 0.f;
#pragma unroll
            for (int x=0;x<16;x++) s += red[tid][x];
            atomicAdd(&alphaP[(size_t)(row0+tid)*4 + h], s);
        }
    }
}

// ---------------- fused phiC recurrence: 16 GRU steps, row-parallel over services ----------------
// grid = S/8 blocks x 128 threads. h in LDS; gh = h @ Whh + bhh computed per step
// (thread owns cols j, j+128, j+256); gi precomputed per-fragment (giF).
__launch_bounds__(128)
__global__ void k_recur(float* __restrict__ h_srv, const float* __restrict__ giF,
                        const float* __restrict__ Whh, const float* __restrict__ bhh,
                        const int* __restrict__ inv, float* __restrict__ out_f,
                        int S, int L, int F)
{
    __shared__ float hs[8][128];
    __shared__ float gh[8][384];
    __shared__ int fLoc[8];
    int tid = threadIdx.x;
    int s0 = blockIdx.x * 8;
    for (int u = tid; u < 1024; u += 128){ int s=u>>7,k=u&127; hs[s][k] = h_srv[(size_t)(s0+s)*128+k]; }
    int j0 = tid, j1 = tid+128, j2 = tid+256;
    float bb0 = bhh[j0], bb1 = bhh[j1], bb2 = bhh[j2];
    for (int t=0;t<L;++t){
        if (tid < 8) fLoc[tid] = inv[(size_t)(s0+tid)*L + t];
        __syncthreads();
        float a0[8],a1[8],a2[8];
#pragma unroll
        for (int s=0;s<8;s++){ a0[s]=bb0; a1[s]=bb1; a2[s]=bb2; }
        for (int k4=0;k4<128;k4+=4){
            float4 hv[8];
#pragma unroll
            for (int s=0;s<8;s++) hv[s] = *(const float4*)&hs[s][k4];
#pragma unroll
            for (int kk=0;kk<4;kk++){
                const float* wr = Whh + (size_t)(k4+kk)*384;
                float w0 = wr[j0], w1 = wr[j1], w2 = wr[j2];
#pragma unroll
                for (int s=0;s<8;s++){
                    float hk = (&hv[s].x)[kk];
                    a0[s] += hk*w0; a1[s] += hk*w1; a2[s] += hk*w2;
                }
            }
        }
#pragma unroll
        for (int s=0;s<8;s++){ gh[s][j0]=a0[s]; gh[s][j1]=a1[s]; gh[s][j2]=a2[s]; }
        __syncthreads();
        for (int u = tid; u < 1024; u += 128){
            int s=u>>7, k=u&127; int f = fLoc[s];
            if (f >= 0 && f < F){
                const float* gp = giF + (size_t)f*384;
                float r  = sigf(gp[k]     + gh[s][k]);
                float zz = sigf(gp[128+k] + gh[s][128+k]);
                float n  = tanhf(gp[256+k] + r*gh[s][256+k]);
                float hn = (1.f-zz)*n + zz*hs[s][k];
                hs[s][k] = hn;
                out_f[(size_t)f*128+k] = hn;
            }
        }
        __syncthreads();
    }
    for (int u = tid; u < 1024; u += 128){ int s=u>>7,k=u&127; h_srv[(size_t)(s0+s)*128+k] = hs[s][k]; }
}

// ---------------- GRU pointwise (gate order r,z,n); in-place capable ----------------
__global__ void k_gru(const float* __restrict__ gi, const float* __restrict__ gh,
                      const float* __restrict__ hin, float* __restrict__ hout, int M)
{
    int idx = blockIdx.x*blockDim.x + threadIdx.x;
    int i = idx >> 7, j = idx & 127;
    if (i >= M) return;
    size_t g = (size_t)i*384;
    float r = sigf(gi[g+j]     + gh[g+j]);
    float z = sigf(gi[g+128+j] + gh[g+128+j]);
    float n = tanhf(gi[g+256+j] + r*gh[g+256+j]);
    float hv = hin[(size_t)i*128+j];
    hout[(size_t)i*128+j] = (1.f-z)*n + z*hv;
}

// ---------------- per-device softmax + weighted [out_f|fragOld] sum ----------------
__global__ void k_attn_z(const float* __restrict__ out_f, const float* __restrict__ fragOld,
                         const float* __restrict__ alpha,
                         const int* __restrict__ list, const int* __restrict__ offs,
                         float* __restrict__ z, float* __restrict__ sa, int Dn, int F)
{
    int d = blockIdx.x;
    int tid = threadIdx.x;
    int h = tid >> 6, lane = tid & 63;
    int beg = offs[d], end = offs[d+1];
    if (beg < 0) beg = 0; if (end > F) end = F; if (end < beg) end = beg;
    float amax = -3.4e38f;
    for (int i=beg;i<end;i++) amax = fmaxf(amax, alpha[(size_t)list[i]*4+h]);
    float wsum = 0.f;
    for (int i=beg;i<end;i++) wsum += expf(alpha[(size_t)list[i]*4+h]-amax);
    float iws = 1.f/(wsum + 1e-16f);
    float acc[4] = {0,0,0,0};
    for (int i=beg;i<end;i++){
        int f = list[i];
        float a = expf(alpha[(size_t)f*4+h]-amax)*iws;
#pragma unroll
        for (int q=0;q<4;q++){
            int c = lane + q*64;
            float v = (c < 128) ? out_f[(size_t)f*128 + c] : fragOld[(size_t)f*128 + c - 128];
            acc[q] += a * v;
        }
    }
#pragma unroll
    for (int q=0;q<4;q++) z[(size_t)d*1024 + h*256 + lane + q*64] = acc[q];
    if (lane == 0) sa[d*4+h] = (end>beg) ? wsum*iws : 0.f;
}

// ---------------- msgD correction: += bias_att + 0.25*sum_h sa[d,h]*b_src[h*256+c]
__global__ void k_msgd_fix(float* __restrict__ msgD, const float* __restrict__ sa,
                           const float* __restrict__ bsrc, const float* __restrict__ batt, int Dn)
{
    int idx = blockIdx.x*blockDim.x + threadIdx.x;
    int d = idx >> 8, c = idx & 255;
    if (d >= Dn) return;
    float v = batt[c];
#pragma unroll
    for (int h=0;h<4;h++) v += 0.25f * sa[d*4+h] * bsrc[h*256+c];
    msgD[(size_t)d*256 + c] += v;
}

// ---------------- scatter 128-wide rows into state by node index ----------------
__global__ void k_scatter(const float* __restrict__ buf, const int* __restrict__ idx,
                          float* __restrict__ state, int M, int nodes)
{
    int t = blockIdx.x*blockDim.x + threadIdx.x;
    int i = t >> 7, j = t & 127;
    if (i >= M) return;
    state[(size_t)clampi(idx[i],0,nodes-1)*128 + j] = buf[(size_t)i*128 + j];
}

// ---------------- device fragment list build (counting sort) ----------------
__global__ void k_count(const int* __restrict__ row, int* __restrict__ counts, int F, int Dn)
{ int f = blockIdx.x*blockDim.x + threadIdx.x; if (f < F) atomicAdd(&counts[clampi(row[f],0,Dn-1)], 1); }

__global__ void k_scan(const int* __restrict__ counts, int* __restrict__ offs, int D)
{
    __shared__ int part[257];
    int tid = threadIdx.x;
    int per = (D + 255) / 256;
    int s = 0;
    for (int i=0;i<per;i++){ int idx = tid*per+i; if (idx < D) s += counts[idx]; }
    part[tid] = s;
    __syncthreads();
    if (tid == 0){
        int acc = 0;
        for (int i=0;i<256;i++){ int v = part[i]; part[i] = acc; acc += v; }
        part[256] = acc;
    }
    __syncthreads();
    int acc = part[tid];
    for (int i=0;i<per;i++){ int idx = tid*per+i; if (idx < D){ offs[idx] = acc; acc += counts[idx]; } }
    if (tid == 0) offs[D] = part[256];
}

__global__ void k_fill(const int* __restrict__ row, const int* __restrict__ offs,
                       int* __restrict__ cursor, int* __restrict__ list, int F, int Dn)
{
    int f = blockIdx.x*blockDim.x + threadIdx.x;
    if (f >= F) return;
    int r = clampi(row[f],0,Dn-1);
    int p = atomicAdd(&cursor[r], 1);
    int pos = offs[r]+p;
    if (pos >= 0 && pos < F) list[pos] = f;
}

__global__ void k_build_inv(const int* __restrict__ fs, const int* __restrict__ fp,
                            int* __restrict__ inv, int F, int L, int S)
{
    int f = blockIdx.x*blockDim.x + threadIdx.x;
    if (f >= F) return;
    inv[clampi(fs[f],0,S-1)*L + clampi(fp[f],0,L-1)] = f;
}

// ---------------- pooling + readout ----------------
__global__ void k_pool_add(const float* __restrict__ frag, const int* __restrict__ fs,
                           float* __restrict__ pooled, int F, int S)
{
    int t = blockIdx.x*blockDim.x + threadIdx.x;
    int i = t >> 7, j = t & 127;
    if (i >= F) return;
    atomicAdd(&pooled[(size_t)clampi(fs[i],0,S-1)*128 + j], frag[(size_t)i*128 + j]);
}

__global__ void k_pool_div(float* __restrict__ pooled, const int* __restrict__ lengths, int S)
{
    int t = blockIdx.x*blockDim.x + threadIdx.x;
    int i = t >> 7, j = t & 127;
    if (i >= S) return;
    int l = lengths[i]; if (l < 1) l = 1;
    pooled[(size_t)i*128 + j] /= (float)l;
}

__global__ void k_dot_out(const float* __restrict__ H, const float* __restrict__ W3,
                          const float* __restrict__ b3, float* __restrict__ outv, int off)
{
    __shared__ float red[256];
    int s = blockIdx.x, tid = threadIdx.x;
    red[tid] = H[(size_t)s*256 + tid] * W3[tid];
    __syncthreads();
    for (int st=128; st; st>>=1){ if (tid < st) red[tid] += red[tid+st]; __syncthreads(); }
    if (tid == 0) outv[off + s] = red[0] + b3[0];
}

// =====================================================================================
extern "C" void kernel_launch(void* const* d_in, const int* in_sizes, int n_in,
                              void* d_out, int out_size, void* d_ws, size_t ws_size,
                              hipStream_t stream)
{
    (void)n_in; (void)out_size; (void)ws_size;
    const float* realnode = (const float*)d_in[0];
    const float* arr      = (const float*)d_in[1];
    const int* r_exe   = (const int*)d_in[2];
    const int* r_idev  = (const int*)d_in[3];
    const int* r_ifrag = (const int*)d_in[4];
    const int* r_fdn   = (const int*)d_in[5];
    const int* r_fdr   = (const int*)d_in[6];
    const int* r_len   = (const int*)d_in[7];
    const int* r_fsvc  = (const int*)d_in[8];
    const int* r_fpos  = (const int*)d_in[9];
    const float *W_dev=(const float*)d_in[10], *b_dev=(const float*)d_in[11];
    const float *W_frg=(const float*)d_in[12], *b_frg=(const float*)d_in[13];
    const float *W_srv=(const float*)d_in[14], *b_srv=(const float*)d_in[15];
    const float *C_Wih=(const float*)d_in[16], *C_Whh=(const float*)d_in[17], *C_bih=(const float*)d_in[18], *C_bhh=(const float*)d_in[19];
    const float *F_Wih=(const float*)d_in[20], *F_Whh=(const float*)d_in[21], *F_bih=(const float*)d_in[22], *F_bhh=(const float*)d_in[23];
    const float *D_Wih=(const float*)d_in[24], *D_Whh=(const float*)d_in[25], *D_bih=(const float*)d_in[26], *D_bhh=(const float*)d_in[27];
    const float *W_src=(const float*)d_in[28], *b_src=(const float*)d_in[29];
    const float *W_tgt=(const float*)d_in[30], *b_tgt=(const float*)d_in[31];
    const float *att=(const float*)d_in[32], *bias_att=(const float*)d_in[33];
    const float *Wt1=(const float*)d_in[34], *bt1=(const float*)d_in[35], *Wt2=(const float*)d_in[36], *bt2=(const float*)d_in[37], *Wt3=(const float*)d_in[38], *bt3=(const float*)d_in[39];
    const float *Wl1=(const float*)d_in[40], *bl1=(const float*)d_in[41], *Wl2=(const float*)d_in[42], *bl2=(const float*)d_in[43], *Wl3=(const float*)d_in[44], *bl3=(const float*)d_in[45];
    float* outp = (float*)d_out;

    const int S  = in_sizes[7];              // 2048
    const int Dn = in_sizes[3];              // 4096
    const int F  = in_sizes[4];              // 20480
    const int L  = in_sizes[2] / (2*S);      // 16
    const int nreal = in_sizes[0]/5;         // 24576
    const int nodes = nreal + 1;             // 24577
    const int NIT = 3;
    const int FH = F/2;                      // 10240

    // ---- workspace arena (~108 MB) ----
    char* wp = (char*)d_ws;
    auto alloc = [&](size_t nelem)->float*{
        float* p = (float*)wp;
        wp += ((nelem*4 + 255)/256)*256;
        return p;
    };
    float* state  = alloc((size_t)nodes*128);
    float* h_srv  = alloc((size_t)S*128);
    float* out_f  = alloc((size_t)F*128);
    float* fragA  = alloc((size_t)F*128);
    float* devA   = alloc((size_t)Dn*128);
    float* alphaB = alloc((size_t)F*4);
    float* msgDm  = alloc((size_t)Dn*256);
    float* saB    = alloc((size_t)Dn*4);
    float* giF    = alloc((size_t)F*384);
    float* TGT    = alloc((size_t)Dn*1024);   // tgt | F-gi chunk | D-gi | readout h1
    float* Z      = alloc((size_t)Dn*1024);   // z   | F-gh chunk | D-gh | readout h2
    float* pooled = alloc((size_t)S*128);
    int* cExe   = (int*)alloc((size_t)S*2*L);
    int* cIdev  = (int*)alloc((size_t)Dn);
    int* cIfrag = (int*)alloc((size_t)F);
    int* cFdn   = (int*)alloc((size_t)F);
    int* cFdr   = (int*)alloc((size_t)F);
    int* cLen   = (int*)alloc((size_t)S);
    int* cFsvc  = (int*)alloc((size_t)F);
    int* cFpos  = (int*)alloc((size_t)F);
    int* inv    = (int*)alloc((size_t)S*L);
    int* counts = (int*)alloc((size_t)Dn);
    int* offs   = (int*)alloc((size_t)Dn+1);
    int* cursor = (int*)alloc((size_t)Dn);
    int* list   = (int*)alloc((size_t)F);

    // ---- int width detection + conversion ----
    const int* det = r_idev;
    auto cvt = [&](const int* src, int* dst, int n){
        k_cvt<<<dim3((n+255)/256),256,0,stream>>>(src, dst, n, det);
    };
    cvt(r_exe,  cExe,  S*2*L);
    cvt(r_idev, cIdev, Dn);
    cvt(r_ifrag,cIfrag,F);
    cvt(r_fdn,  cFdn,  F);
    cvt(r_fdr,  cFdr,  F);
    cvt(r_len,  cLen,  S);
    cvt(r_fsvc, cFsvc, F);
    cvt(r_fpos, cFpos, F);

    hipMemsetAsync(state, 0, (size_t)nodes*128*4, stream);
    hipMemsetAsync(inv, 0xFF, (size_t)S*L*4, stream);
    hipMemsetAsync(counts, 0, (size_t)Dn*4, stream);
    hipMemsetAsync(cursor, 0, (size_t)Dn*4, stream);

    k_proj5<<<dim3((Dn*128+255)/256),256,0,stream>>>(realnode, W_dev, b_dev, cIdev, cIdev, state, devA, Dn, nreal, nodes);
    k_proj5<<<dim3(((size_t)F*128+255)/256),256,0,stream>>>(realnode, W_frg, b_frg, cIfrag, cIfrag, state, fragA, F, nreal, nodes);
    k_proj5<<<dim3((S*128+255)/256),256,0,stream>>>(arr, W_srv, b_srv, nullptr, nullptr, h_srv, nullptr, S, S, nodes);
    k_build_inv<<<dim3((F+255)/256),256,0,stream>>>(cFsvc, cFpos, inv, F, L, S);
    k_count<<<dim3((F+255)/256),256,0,stream>>>(cFdr, counts, F, Dn);
    k_scan<<<1,256,0,stream>>>(counts, offs, Dn);
    k_fill<<<dim3((F+255)/256),256,0,stream>>>(cFdr, offs, cursor, list, F, Dn);

    for (int it=0; it<NIT; ++it){
        // ---- phiC: batched gi over valid (s,t) == fragments; then fused recurrence ----
        k_mm<<<dim3(384/128, F/128),256,0,stream>>>(state, state, cIfrag, cFdn, 0,
            C_Wih, 384, C_bih, giF, F, 384, 256, 0, 1.f, 0, 0, nullptr, nullptr, nullptr, nullptr, nullptr);
        k_recur<<<dim3(S/8),128,0,stream>>>(h_srv, giF, C_Whh, C_bhh, inv, out_f, S, L, F);
        // ---- attention ----
        k_mm<<<dim3(1024/128, Dn/128),256,0,stream>>>(devA, nullptr, nullptr, nullptr, 128,
            W_tgt, 1024, b_tgt, TGT, Dn, 1024, 128, 0, 1.f, 0, 0, nullptr, nullptr, nullptr, nullptr, nullptr);
        hipMemsetAsync(alphaB, 0, (size_t)F*4*4, stream);
        k_mm<<<dim3(1024/128, F/128),256,0,stream>>>(out_f, fragA, nullptr, nullptr, 0,
            W_src, 1024, nullptr, nullptr, F, 1024, 256, 0, 1.f, 0, 1, TGT, cFdr, att, b_src, alphaB);
        k_attn_z<<<dim3(Dn),256,0,stream>>>(out_f, fragA, alphaB, list, offs, Z, saB, Dn, F);
        for (int h=0;h<4;h++)
            k_mm<<<dim3(256/128, Dn/128),256,0,stream>>>(Z + h*256, nullptr, nullptr, nullptr, 1024,
                W_src + h*256, 1024, nullptr, msgDm, Dn, 256, 256, 0, 0.25f, h>0, 0, nullptr, nullptr, nullptr, nullptr, nullptr);
        k_msgd_fix<<<dim3((Dn*256+255)/256),256,0,stream>>>(msgDm, saB, b_src, bias_att, Dn);
        // ---- F-GRU, chunked 2x (in-place on fragA) ----
        for (int c=0;c<2;c++){
            size_t off = (size_t)c*FH;
            k_mm<<<dim3(384/128, FH/128),256,0,stream>>>(out_f + off*128, state, nullptr, cFdn + off, 0,
                F_Wih, 384, F_bih, TGT, FH, 384, 256, 0, 1.f, 0, 0, nullptr, nullptr, nullptr, nullptr, nullptr);
            k_mm<<<dim3(384/128, FH/128),256,0,stream>>>(fragA + off*128, nullptr, nullptr, nullptr, 128,
                F_Whh, 384, F_bhh, Z, FH, 384, 128, 0, 1.f, 0, 0, nullptr, nullptr, nullptr, nullptr, nullptr);
            k_gru<<<dim3(((size_t)FH*128+255)/256),256,0,stream>>>(TGT, Z, fragA + off*128, fragA + off*128, FH);
        }
        // ---- D-GRU (in-place on devA) ----
        k_mm<<<dim3(384/128, Dn/128),256,0,stream>>>(msgDm, nullptr, nullptr, nullptr, 256,
            D_Wih, 384, D_bih, TGT, Dn, 384, 256, 0, 1.f, 0, 0, nullptr, nullptr, nullptr, nullptr, nullptr);
        k_mm<<<dim3(384/128, Dn/128),256,0,stream>>>(devA, nullptr, nullptr, nullptr, 128,
            D_Whh, 384, D_bhh, Z, Dn, 384, 128, 0, 1.f, 0, 0, nullptr, nullptr, nullptr, nullptr, nullptr);
        k_gru<<<dim3((Dn*128+255)/256),256,0,stream>>>(TGT, Z, devA, devA, Dn);
        // ---- scatter updated states into node table ----
        k_scatter<<<dim3(((size_t)F*128+255)/256),256,0,stream>>>(fragA, cIfrag, state, F, nodes);
        k_scatter<<<dim3((Dn*128+255)/256),256,0,stream>>>(devA, cIdev, state, Dn, nodes);
    }

    // ---- readout ----
    hipMemsetAsync(pooled, 0, (size_t)S*128*4, stream);
    k_pool_add<<<dim3(((size_t)F*128+255)/256),256,0,stream>>>(fragA, cFsvc, pooled, F, S);
    k_pool_div<<<dim3((S*128+255)/256),256,0,stream>>>(pooled, cLen, S);
    // latency head (pooled)
    k_mm<<<dim3(256/128, S/128),256,0,stream>>>(pooled, nullptr, nullptr, nullptr, 128,
        Wl1, 256, bl1, TGT, S, 256, 128, 1, 1.f, 0, 0, nullptr, nullptr, nullptr, nullptr, nullptr);
    k_mm<<<dim3(256/128, S/128),256,0,stream>>>(TGT, nullptr, nullptr, nullptr, 256,
        Wl2, 256, bl2, Z, S, 256, 256, 1, 1.f, 0, 0, nullptr, nullptr, nullptr, nullptr, nullptr);
    k_dot_out<<<dim3(S),256,0,stream>>>(Z, Wl3, bl3, outp, 0);
    // throughput head (h_srv)
    k_mm<<<dim3(256/128, S/128),256,0,stream>>>(h_srv, nullptr, nullptr, nullptr, 128,
        Wt1, 256, bt1, TGT, S, 256, 128, 1, 1.f, 0, 0, nullptr, nullptr, nullptr, nullptr, nullptr);
    k_mm<<<dim3(256/128, S/128),256,0,stream>>>(TGT, nullptr, nullptr, nullptr, 256,
        Wt2, 256, bt2, Z, S, 256, 256, 1, 1.f, 0, 0, nullptr, nullptr, nullptr, nullptr, nullptr);
    k_dot_out<<<dim3(S),256,0,stream>>>(Z, Wt3, bt3, outp, S);
}

// Round 5
// 1975.930 us; speedup vs baseline: 1.9877x; 1.3910x over previous
//
#include <hip/hip_runtime.h>
#include <hip/hip_bf16.h>

typedef __attribute__((ext_vector_type(8))) short bf16x8;
typedef __attribute__((ext_vector_type(4))) float f32x4;

__device__ __forceinline__ float sigf(float x){ return 1.0f/(1.0f+expf(-x)); }
__device__ __forceinline__ int clampi(int v, int lo, int hi){ return v<lo?lo:(v>hi?hi:v); }
__device__ __forceinline__ unsigned short f2b(float f){
    __hip_bfloat16 h = __float2bfloat16(f);
    return *reinterpret_cast<unsigned short*>(&h);
}

// ---- int64/int32 tolerant index conversion ----
__global__ void k_cvt(const int* __restrict__ src, int* __restrict__ dst, int n,
                      const int* __restrict__ det)
{
    int i = blockIdx.x*blockDim.x + threadIdx.x;
    if (i >= n) return;
    int stride = (det[1] == 0) ? 2 : 1;
    dst[i] = src[(size_t)i*stride];
}

// ---- weight transpose+convert: Wt[n][k] (bf16) <- W[k][n] (f32) ----
__global__ void k_wt(const float* __restrict__ W, unsigned short* __restrict__ Wt,
                     int N, int kshift, int kmask, int total)
{
    int idx = blockIdx.x*blockDim.x + threadIdx.x;
    if (idx >= total) return;
    int n = idx >> kshift, k = idx & kmask;
    Wt[idx] = f2b(W[(size_t)k*N + n]);
}

// ---------------- init projections ----------------
__global__ void k_proj5(const float* __restrict__ X, const float* __restrict__ W,
                        const float* __restrict__ bias,
                        const int* __restrict__ gidx, const int* __restrict__ sidx,
                        float* __restrict__ out, float* __restrict__ out2, int M, int nrows, int nodes)
{
    int t = blockIdx.x*blockDim.x + threadIdx.x;
    int i = t >> 7, j = t & 127;
    if (i >= M) return;
    int src = gidx ? clampi(gidx[i]-1, 0, nrows-1) : i;
    const float* xp = X + (size_t)src*5;
    float acc = bias[j];
#pragma unroll
    for (int k=0;k<5;k++) acc += xp[k] * W[k*128+j];
    int dr = sidx ? clampi(sidx[i], 0, nodes-1) : i;
    out[(size_t)dr*128 + j] = acc;
    if (out2) out2[(size_t)i*128 + j] = acc;
}

// ---------------- f32 tiled GEMM (kept for small/accumulating GEMMs) ----------------
__launch_bounds__(256)
__global__ void k_mm(const float* __restrict__ A0, int lda,
                     const float* __restrict__ B, int ldb,
                     const float* __restrict__ bias, float* __restrict__ C,
                     int M, int N, int K, int relu, float scale, int accum)
{
    __shared__ float As[16][132];
    __shared__ float Bs[16][132];
    int tid = threadIdx.x;
    int tx = tid & 15, ty = tid >> 4;
    int row0 = blockIdx.y * 128, col0 = blockIdx.x * 128;
    float acc[8][8] = {};
    for (int k0 = 0; k0 < K; k0 += 16){
#pragma unroll
        for (int q = 0; q < 2; ++q){
            int idx = tid + q*256;
            int r = idx >> 2, k4 = (idx & 3) * 4;
            const float* src = A0 + (size_t)(row0+r)*lda + k0 + k4;
            float4 v = *reinterpret_cast<const float4*>(src);
            As[k4+0][r]=v.x; As[k4+1][r]=v.y; As[k4+2][r]=v.z; As[k4+3][r]=v.w;
        }
#pragma unroll
        for (int q = 0; q < 2; ++q){
            int idx = tid + q*256;
            int kb = idx >> 5, n4 = (idx & 31) * 4;
            float4 v = *reinterpret_cast<const float4*>(B + (size_t)(k0+kb)*ldb + col0 + n4);
            *reinterpret_cast<float4*>(&Bs[kb][n4]) = v;
        }
        __syncthreads();
#pragma unroll
        for (int k = 0; k < 16; ++k){
            float a[8], b[8];
            *(float4*)&a[0] = *(const float4*)&As[k][ty*8];
            *(float4*)&a[4] = *(const float4*)&As[k][ty*8+4];
            *(float4*)&b[0] = *(const float4*)&Bs[k][tx*8];
            *(float4*)&b[4] = *(const float4*)&Bs[k][tx*8+4];
#pragma unroll
            for (int i=0;i<8;i++)
#pragma unroll
                for (int j=0;j<8;j++) acc[i][j] += a[i]*b[j];
        }
        __syncthreads();
    }
    float bb[8];
#pragma unroll
    for (int j=0;j<8;j++) bb[j] = bias ? bias[col0+tx*8+j] : 0.f;
#pragma unroll
    for (int i=0;i<8;i++){
        float* cp = C + (size_t)(row0+ty*8+i)*N + col0 + tx*8;
#pragma unroll
        for (int jq=0;jq<2;jq++){
            float4 prev = accum ? *(const float4*)(cp+jq*4) : make_float4(0,0,0,0);
            float o[4];
#pragma unroll
            for (int c=0;c<4;c++){
                float u = acc[i][jq*4+c] + bb[jq*4+c];
                if (relu) u = fmaxf(u,0.f);
                o[c] = (&prev.x)[c] + scale*u;
            }
            *(float4*)(cp+jq*4) = make_float4(o[0],o[1],o[2],o[3]);
        }
    }
}

// ---------------- bf16 MFMA GEMM: C[M,N] = A(f32->bf16) @ Wt^T + bias ----------------
// Wt is bf16 [N][K] row-major. A modes as before (two-half indexed if A1!=null).
// epi==0: C = AB + bias (f32).  epi==1: GAT alpha epilogue -> atomicAdd(alphaP).
// Tile 128x128, 4 waves (2x2), 4x4 frags of mfma_f32_16x16x32_bf16, BK=64.
__launch_bounds__(256)
__global__ void mm_bf(const float* __restrict__ A0, const float* __restrict__ A1,
                      const int* __restrict__ i0, const int* __restrict__ i1, int lda,
                      const unsigned short* __restrict__ Wt,
                      const float* __restrict__ bias, float* __restrict__ C,
                      int M, int N, int K, int epi,
                      const float* __restrict__ tgtP, const int* __restrict__ rowIdx,
                      const float* __restrict__ attP, const float* __restrict__ bsrcP,
                      float* __restrict__ alphaP)
{
    __shared__ alignas(16) unsigned short As[128*64];
    __shared__ alignas(16) unsigned short Bs[128*64];
    int tid = threadIdx.x;
    int l = tid & 63, w = tid >> 6;
    int wr = w >> 1, wc = w & 1;
    int row0 = blockIdx.y * 128, col0 = blockIdx.x * 128;
    f32x4 acc[4][4];
#pragma unroll
    for (int m=0;m<4;m++)
#pragma unroll
        for (int n=0;n<4;n++) acc[m][n] = (f32x4){0.f,0.f,0.f,0.f};

    for (int k0 = 0; k0 < K; k0 += 64){
        // stage A (f32 -> bf16, swizzled)
#pragma unroll
        for (int q = 0; q < 8; ++q){
            int idx = tid + q*256;
            int r = idx >> 4, c4 = (idx & 15) * 4;
            int kk = k0 + c4;
            const float* src;
            if (A1){
                if (kk < 128){ int ri = i0 ? i0[row0+r] : (row0+r); src = A0 + (size_t)ri*128 + kk; }
                else         { int ri = i1 ? i1[row0+r] : (row0+r); src = A1 + (size_t)ri*128 + (kk-128); }
            } else {
                src = A0 + (size_t)(row0+r)*lda + kk;
            }
            float4 v = *reinterpret_cast<const float4*>(src);
            ushort4 o; o.x=f2b(v.x); o.y=f2b(v.y); o.z=f2b(v.z); o.w=f2b(v.w);
            int csw = c4 ^ ((r & 7) << 3);
            *reinterpret_cast<ushort4*>(&As[r*64 + csw]) = o;
        }
        // stage B from Wt[n][k] (bf16, already transposed)
#pragma unroll
        for (int q = 0; q < 4; ++q){
            int idx = tid + q*256;
            int n = idx >> 3, k8 = (idx & 7) * 8;
            uint4 v = *reinterpret_cast<const uint4*>(Wt + (size_t)(col0+n)*K + k0 + k8);
            int ksw = k8 ^ ((n & 7) << 3);
            *reinterpret_cast<uint4*>(&Bs[n*64 + ksw]) = v;
        }
        __syncthreads();
#pragma unroll
        for (int kk = 0; kk < 2; ++kk){
            int ek = kk*32 + (l >> 4) * 8;
            bf16x8 af[4], bf[4];
#pragma unroll
            for (int m=0;m<4;m++){
                int r = wr*64 + m*16 + (l & 15);
                af[m] = *reinterpret_cast<const bf16x8*>(&As[r*64 + (ek ^ ((r & 7) << 3))]);
            }
#pragma unroll
            for (int n=0;n<4;n++){
                int c = wc*64 + n*16 + (l & 15);
                bf[n] = *reinterpret_cast<const bf16x8*>(&Bs[c*64 + (ek ^ ((c & 7) << 3))]);
            }
#pragma unroll
            for (int m=0;m<4;m++)
#pragma unroll
                for (int n=0;n<4;n++)
                    acc[m][n] = __builtin_amdgcn_mfma_f32_16x16x32_bf16(af[m], bf[n], acc[m][n], 0, 0, 0);
        }
        __syncthreads();
    }

    if (epi == 0){
#pragma unroll
        for (int m=0;m<4;m++){
#pragma unroll
            for (int v=0;v<4;v++){
                int row = row0 + wr*64 + m*16 + (l >> 4)*4 + v;
                float* cp = C + (size_t)row*N + col0 + wc*64 + (l & 15);
#pragma unroll
                for (int n=0;n<4;n++){
                    int col = col0 + wc*64 + n*16 + (l & 15);
                    float u = acc[m][n][v] + (bias ? bias[col] : 0.f);
                    cp[n*16] = u;
                }
            }
        }
    } else {
        int h = col0 >> 8;
#pragma unroll
        for (int m=0;m<4;m++){
#pragma unroll
            for (int v=0;v<4;v++){
                int rglob = row0 + wr*64 + m*16 + (l >> 4)*4 + v;
                int dr = rowIdx[rglob];
                const float* tp = tgtP + (size_t)dr*1024 + col0 + wc*64;
                float s = 0.f;
#pragma unroll
                for (int n=0;n<4;n++){
                    int cl = n*16 + (l & 15);
                    int c = col0 + wc*64 + cl;
                    float e = acc[m][n][v] + bsrcP[c] + tp[cl];
                    e = e > 0.f ? e : 0.2f*e;
                    s += e * attP[c];
                }
#pragma unroll
                for (int msk=1; msk<16; msk<<=1) s += __shfl_xor(s, msk);
                if ((l & 15) == 0) atomicAdd(&alphaP[(size_t)rglob*4 + h], s);
            }
        }
    }
}

// ---------------- fused phiC recurrence: 384 threads, 8 services/block ----------------
__launch_bounds__(384)
__global__ void k_recur(float* __restrict__ h_srv, const float* __restrict__ giF,
                        const float* __restrict__ Whh, const float* __restrict__ bhh,
                        const int* __restrict__ inv, float* __restrict__ out_f,
                        int S, int L, int F)
{
    __shared__ float hs[8][128];
    __shared__ float ghs[8][384];
    __shared__ int fLoc[8];
    int tid = threadIdx.x;
    int s0 = blockIdx.x * 8;
    for (int u = tid; u < 1024; u += 384){ int s=u>>7,k=u&127; hs[s][k] = h_srv[(size_t)(s0+s)*128+k]; }
    float bb = bhh[tid];
    for (int t=0;t<L;++t){
        if (tid < 8) fLoc[tid] = inv[(size_t)(s0+tid)*L + t];
        __syncthreads();
        float a[8];
#pragma unroll
        for (int s=0;s<8;s++) a[s] = bb;
        for (int k4=0;k4<128;k4+=4){
            float4 hv[8];
#pragma unroll
            for (int s=0;s<8;s++) hv[s] = *(const float4*)&hs[s][k4];
#pragma unroll
            for (int kk=0;kk<4;kk++){
                float wv = Whh[(size_t)(k4+kk)*384 + tid];
#pragma unroll
                for (int s=0;s<8;s++) a[s] += (&hv[s].x)[kk] * wv;
            }
        }
#pragma unroll
        for (int s=0;s<8;s++) ghs[s][tid] = a[s];
        __syncthreads();
        for (int u = tid; u < 1024; u += 384){
            int s=u>>7, k=u&127; int f = fLoc[s];
            if (f >= 0 && f < F){
                const float* gp = giF + (size_t)f*384;
                float r  = sigf(gp[k]     + ghs[s][k]);
                float zz = sigf(gp[128+k] + ghs[s][128+k]);
                float n  = tanhf(gp[256+k] + r*ghs[s][256+k]);
                float hn = (1.f-zz)*n + zz*hs[s][k];
                hs[s][k] = hn;
                out_f[(size_t)f*128+k] = hn;
            }
        }
        __syncthreads();
    }
    for (int u = tid; u < 1024; u += 384){ int s=u>>7,k=u&127; h_srv[(size_t)(s0+s)*128+k] = hs[s][k]; }
}

// ---------------- GRU pointwise ----------------
__global__ void k_gru(const float* __restrict__ gi, const float* __restrict__ gh,
                      const float* __restrict__ hin, float* __restrict__ hout, int M)
{
    int idx = blockIdx.x*blockDim.x + threadIdx.x;
    int i = idx >> 7, j = idx & 127;
    if (i >= M) return;
    size_t g = (size_t)i*384;
    float r = sigf(gi[g+j]     + gh[g+j]);
    float z = sigf(gi[g+128+j] + gh[g+128+j]);
    float n = tanhf(gi[g+256+j] + r*gh[g+256+j]);
    float hv = hin[(size_t)i*128+j];
    hout[(size_t)i*128+j] = (1.f-z)*n + z*hv;
}

// ---------------- per-device softmax + weighted [out_f|fragOld] sum ----------------
__global__ void k_attn_z(const float* __restrict__ out_f, const float* __restrict__ fragOld,
                         const float* __restrict__ alpha,
                         const int* __restrict__ list, const int* __restrict__ offs,
                         float* __restrict__ z, float* __restrict__ sa, int Dn, int F)
{
    int d = blockIdx.x;
    int tid = threadIdx.x;
    int h = tid >> 6, lane = tid & 63;
    int beg = offs[d], end = offs[d+1];
    if (beg < 0) beg = 0; if (end > F) end = F; if (end < beg) end = beg;
    float amax = -3.4e38f;
    for (int i=beg;i<end;i++) amax = fmaxf(amax, alpha[(size_t)list[i]*4+h]);
    float wsum = 0.f;
    for (int i=beg;i<end;i++) wsum += expf(alpha[(size_t)list[i]*4+h]-amax);
    float iws = 1.f/(wsum + 1e-16f);
    float acc[4] = {0,0,0,0};
    for (int i=beg;i<end;i++){
        int f = list[i];
        float a = expf(alpha[(size_t)f*4+h]-amax)*iws;
#pragma unroll
        for (int q=0;q<4;q++){
            int c = lane + q*64;
            float v = (c < 128) ? out_f[(size_t)f*128 + c] : fragOld[(size_t)f*128 + c - 128];
            acc[q] += a * v;
        }
    }
#pragma unroll
    for (int q=0;q<4;q++) z[(size_t)d*1024 + h*256 + lane + q*64] = acc[q];
    if (lane == 0) sa[d*4+h] = (end>beg) ? wsum*iws : 0.f;
}

__global__ void k_msgd_fix(float* __restrict__ msgD, const float* __restrict__ sa,
                           const float* __restrict__ bsrc, const float* __restrict__ batt, int Dn)
{
    int idx = blockIdx.x*blockDim.x + threadIdx.x;
    int d = idx >> 8, c = idx & 255;
    if (d >= Dn) return;
    float v = batt[c];
#pragma unroll
    for (int h=0;h<4;h++) v += 0.25f * sa[d*4+h] * bsrc[h*256+c];
    msgD[(size_t)d*256 + c] += v;
}

__global__ void k_scatter(const float* __restrict__ buf, const int* __restrict__ idx,
                          float* __restrict__ state, int M, int nodes)
{
    int t = blockIdx.x*blockDim.x + threadIdx.x;
    int i = t >> 7, j = t & 127;
    if (i >= M) return;
    state[(size_t)clampi(idx[i],0,nodes-1)*128 + j] = buf[(size_t)i*128 + j];
}

__global__ void k_count(const int* __restrict__ row, int* __restrict__ counts, int F, int Dn)
{ int f = blockIdx.x*blockDim.x + threadIdx.x; if (f < F) atomicAdd(&counts[clampi(row[f],0,Dn-1)], 1); }

__global__ void k_scan(const int* __restrict__ counts, int* __restrict__ offs, int D)
{
    __shared__ int part[257];
    int tid = threadIdx.x;
    int per = (D + 255) / 256;
    int s = 0;
    for (int i=0;i<per;i++){ int idx = tid*per+i; if (idx < D) s += counts[idx]; }
    part[tid] = s;
    __syncthreads();
    if (tid == 0){
        int acc = 0;
        for (int i=0;i<256;i++){ int v = part[i]; part[i] = acc; acc += v; }
        part[256] = acc;
    }
    __syncthreads();
    int acc = part[tid];
    for (int i=0;i<per;i++){ int idx = tid*per+i; if (idx < D){ offs[idx] = acc; acc += counts[idx]; } }
    if (tid == 0) offs[D] = part[256];
}

__global__ void k_fill(const int* __restrict__ row, const int* __restrict__ offs,
                       int* __restrict__ cursor, int* __restrict__ list, int F, int Dn)
{
    int f = blockIdx.x*blockDim.x + threadIdx.x;
    if (f >= F) return;
    int r = clampi(row[f],0,Dn-1);
    int p = atomicAdd(&cursor[r], 1);
    int pos = offs[r]+p;
    if (pos >= 0 && pos < F) list[pos] = f;
}

__global__ void k_build_inv(const int* __restrict__ fs, const int* __restrict__ fp,
                            int* __restrict__ inv, int F, int L, int S)
{
    int f = blockIdx.x*blockDim.x + threadIdx.x;
    if (f >= F) return;
    inv[clampi(fs[f],0,S-1)*L + clampi(fp[f],0,L-1)] = f;
}

__global__ void k_pool_add(const float* __restrict__ frag, const int* __restrict__ fs,
                           float* __restrict__ pooled, int F, int S)
{
    int t = blockIdx.x*blockDim.x + threadIdx.x;
    int i = t >> 7, j = t & 127;
    if (i >= F) return;
    atomicAdd(&pooled[(size_t)clampi(fs[i],0,S-1)*128 + j], frag[(size_t)i*128 + j]);
}

__global__ void k_pool_div(float* __restrict__ pooled, const int* __restrict__ lengths, int S)
{
    int t = blockIdx.x*blockDim.x + threadIdx.x;
    int i = t >> 7, j = t & 127;
    if (i >= S) return;
    int l = lengths[i]; if (l < 1) l = 1;
    pooled[(size_t)i*128 + j] /= (float)l;
}

__global__ void k_dot_out(const float* __restrict__ H, const float* __restrict__ W3,
                          const float* __restrict__ b3, float* __restrict__ outv, int off)
{
    __shared__ float red[256];
    int s = blockIdx.x, tid = threadIdx.x;
    red[tid] = H[(size_t)s*256 + tid] * W3[tid];
    __syncthreads();
    for (int st=128; st; st>>=1){ if (tid < st) red[tid] += red[tid+st]; __syncthreads(); }
    if (tid == 0) outv[off + s] = red[0] + b3[0];
}

// =====================================================================================
extern "C" void kernel_launch(void* const* d_in, const int* in_sizes, int n_in,
                              void* d_out, int out_size, void* d_ws, size_t ws_size,
                              hipStream_t stream)
{
    (void)n_in; (void)out_size; (void)ws_size;
    const float* realnode = (const float*)d_in[0];
    const float* arr      = (const float*)d_in[1];
    const int* r_exe   = (const int*)d_in[2];
    const int* r_idev  = (const int*)d_in[3];
    const int* r_ifrag = (const int*)d_in[4];
    const int* r_fdn   = (const int*)d_in[5];
    const int* r_fdr   = (const int*)d_in[6];
    const int* r_len   = (const int*)d_in[7];
    const int* r_fsvc  = (const int*)d_in[8];
    const int* r_fpos  = (const int*)d_in[9];
    const float *W_dev=(const float*)d_in[10], *b_dev=(const float*)d_in[11];
    const float *W_frg=(const float*)d_in[12], *b_frg=(const float*)d_in[13];
    const float *W_srv=(const float*)d_in[14], *b_srv=(const float*)d_in[15];
    const float *C_Wih=(const float*)d_in[16], *C_Whh=(const float*)d_in[17], *C_bih=(const float*)d_in[18], *C_bhh=(const float*)d_in[19];
    const float *F_Wih=(const float*)d_in[20], *F_Whh=(const float*)d_in[21], *F_bih=(const float*)d_in[22], *F_bhh=(const float*)d_in[23];
    const float *D_Wih=(const float*)d_in[24], *D_Whh=(const float*)d_in[25], *D_bih=(const float*)d_in[26], *D_bhh=(const float*)d_in[27];
    const float *W_src=(const float*)d_in[28], *b_src=(const float*)d_in[29];
    const float *W_tgt=(const float*)d_in[30], *b_tgt=(const float*)d_in[31];
    const float *att=(const float*)d_in[32], *bias_att=(const float*)d_in[33];
    const float *Wt1=(const float*)d_in[34], *bt1=(const float*)d_in[35], *Wt2=(const float*)d_in[36], *bt2=(const float*)d_in[37], *Wt3=(const float*)d_in[38], *bt3=(const float*)d_in[39];
    const float *Wl1=(const float*)d_in[40], *bl1=(const float*)d_in[41], *Wl2=(const float*)d_in[42], *bl2=(const float*)d_in[43], *Wl3=(const float*)d_in[44], *bl3=(const float*)d_in[45];
    float* outp = (float*)d_out;

    const int S  = in_sizes[7];
    const int Dn = in_sizes[3];
    const int F  = in_sizes[4];
    const int L  = in_sizes[2] / (2*S);
    const int nreal = in_sizes[0]/5;
    const int nodes = nreal + 1;
    const int NIT = 3;
    const int FH = F/2;

    char* wp = (char*)d_ws;
    auto alloc = [&](size_t nelem)->float*{
        float* p = (float*)wp;
        wp += ((nelem*4 + 255)/256)*256;
        return p;
    };
    float* state  = alloc((size_t)nodes*128);
    float* h_srv  = alloc((size_t)S*128);
    float* out_f  = alloc((size_t)F*128);
    float* fragA  = alloc((size_t)F*128);
    float* devA   = alloc((size_t)Dn*128);
    float* alphaB = alloc((size_t)F*4);
    float* msgDm  = alloc((size_t)Dn*256);
    float* saB    = alloc((size_t)Dn*4);
    float* giF    = alloc((size_t)F*384);
    float* TGT    = alloc((size_t)Dn*1024);
    float* Z      = alloc((size_t)Dn*1024);
    float* pooled = alloc((size_t)S*128);
    // bf16 transposed weights
    unsigned short* tCWih = (unsigned short*)alloc(384*256/2);
    unsigned short* tFWih = (unsigned short*)alloc(384*256/2);
    unsigned short* tFWhh = (unsigned short*)alloc(384*128/2);
    unsigned short* tDWih = (unsigned short*)alloc(384*256/2);
    unsigned short* tDWhh = (unsigned short*)alloc(384*128/2);
    unsigned short* tWtgt = (unsigned short*)alloc(1024*128/2);
    unsigned short* tWsrc = (unsigned short*)alloc(1024*256/2);
    int* cExe   = (int*)alloc((size_t)S*2*L);
    int* cIdev  = (int*)alloc((size_t)Dn);
    int* cIfrag = (int*)alloc((size_t)F);
    int* cFdn   = (int*)alloc((size_t)F);
    int* cFdr   = (int*)alloc((size_t)F);
    int* cLen   = (int*)alloc((size_t)S);
    int* cFsvc  = (int*)alloc((size_t)F);
    int* cFpos  = (int*)alloc((size_t)F);
    int* inv    = (int*)alloc((size_t)S*L);
    int* counts = (int*)alloc((size_t)Dn);
    int* offs   = (int*)alloc((size_t)Dn+1);
    int* cursor = (int*)alloc((size_t)Dn);
    int* list   = (int*)alloc((size_t)F);

    const int* det = r_idev;
    auto cvt = [&](const int* src, int* dst, int n){
        k_cvt<<<dim3((n+255)/256),256,0,stream>>>(src, dst, n, det);
    };
    cvt(r_exe,  cExe,  S*2*L);
    cvt(r_idev, cIdev, Dn);
    cvt(r_ifrag,cIfrag,F);
    cvt(r_fdn,  cFdn,  F);
    cvt(r_fdr,  cFdr,  F);
    cvt(r_len,  cLen,  S);
    cvt(r_fsvc, cFsvc, F);
    cvt(r_fpos, cFpos, F);

    // transpose+convert weights (once per call)
    k_wt<<<dim3((98304+255)/256),256,0,stream>>>(C_Wih, tCWih, 384, 8, 255, 98304);
    k_wt<<<dim3((98304+255)/256),256,0,stream>>>(F_Wih, tFWih, 384, 8, 255, 98304);
    k_wt<<<dim3((49152+255)/256),256,0,stream>>>(F_Whh, tFWhh, 384, 7, 127, 49152);
    k_wt<<<dim3((98304+255)/256),256,0,stream>>>(D_Wih, tDWih, 384, 8, 255, 98304);
    k_wt<<<dim3((49152+255)/256),256,0,stream>>>(D_Whh, tDWhh, 384, 7, 127, 49152);
    k_wt<<<dim3((131072+255)/256),256,0,stream>>>(W_tgt, tWtgt, 1024, 7, 127, 131072);
    k_wt<<<dim3((262144+255)/256),256,0,stream>>>(W_src, tWsrc, 1024, 8, 255, 262144);

    hipMemsetAsync(state, 0, (size_t)nodes*128*4, stream);
    hipMemsetAsync(inv, 0xFF, (size_t)S*L*4, stream);
    hipMemsetAsync(counts, 0, (size_t)Dn*4, stream);
    hipMemsetAsync(cursor, 0, (size_t)Dn*4, stream);

    k_proj5<<<dim3((Dn*128+255)/256),256,0,stream>>>(realnode, W_dev, b_dev, cIdev, cIdev, state, devA, Dn, nreal, nodes);
    k_proj5<<<dim3(((size_t)F*128+255)/256),256,0,stream>>>(realnode, W_frg, b_frg, cIfrag, cIfrag, state, fragA, F, nreal, nodes);
    k_proj5<<<dim3((S*128+255)/256),256,0,stream>>>(arr, W_srv, b_srv, nullptr, nullptr, h_srv, nullptr, S, S, nodes);
    k_build_inv<<<dim3((F+255)/256),256,0,stream>>>(cFsvc, cFpos, inv, F, L, S);
    k_count<<<dim3((F+255)/256),256,0,stream>>>(cFdr, counts, F, Dn);
    k_scan<<<1,256,0,stream>>>(counts, offs, Dn);
    k_fill<<<dim3((F+255)/256),256,0,stream>>>(cFdr, offs, cursor, list, F, Dn);

    for (int it=0; it<NIT; ++it){
        // phiC: batched gi (MFMA) + fused recurrence
        mm_bf<<<dim3(3, F/128),256,0,stream>>>(state, state, cIfrag, cFdn, 0,
            tCWih, C_bih, giF, F, 384, 256, 0, nullptr, nullptr, nullptr, nullptr, nullptr);
        k_recur<<<dim3(S/8),384,0,stream>>>(h_srv, giF, C_Whh, C_bhh, inv, out_f, S, L, F);
        // attention
        mm_bf<<<dim3(8, Dn/128),256,0,stream>>>(devA, nullptr, nullptr, nullptr, 128,
            tWtgt, b_tgt, TGT, Dn, 1024, 128, 0, nullptr, nullptr, nullptr, nullptr, nullptr);
        hipMemsetAsync(alphaB, 0, (size_t)F*4*4, stream);
        mm_bf<<<dim3(8, F/128),256,0,stream>>>(out_f, fragA, nullptr, nullptr, 0,
            tWsrc, nullptr, nullptr, F, 1024, 256, 1, TGT, cFdr, att, b_src, alphaB);
        k_attn_z<<<dim3(Dn),256,0,stream>>>(out_f, fragA, alphaB, list, offs, Z, saB, Dn, F);
        for (int h=0;h<4;h++)
            k_mm<<<dim3(256/128, Dn/128),256,0,stream>>>(Z + h*256, 1024,
                W_src + h*256, 1024, nullptr, msgDm, Dn, 256, 256, 0, 0.25f, h>0);
        k_msgd_fix<<<dim3((Dn*256+255)/256),256,0,stream>>>(msgDm, saB, b_src, bias_att, Dn);
        // F-GRU chunked 2x
        for (int c=0;c<2;c++){
            size_t off = (size_t)c*FH;
            mm_bf<<<dim3(3, FH/128),256,0,stream>>>(out_f + off*128, state, nullptr, cFdn + off, 0,
                tFWih, F_bih, TGT, FH, 384, 256, 0, nullptr, nullptr, nullptr, nullptr, nullptr);
            mm_bf<<<dim3(3, FH/128),256,0,stream>>>(fragA + off*128, nullptr, nullptr, nullptr, 128,
                tFWhh, F_bhh, Z, FH, 384, 128, 0, nullptr, nullptr, nullptr, nullptr, nullptr);
            k_gru<<<dim3(((size_t)FH*128+255)/256),256,0,stream>>>(TGT, Z, fragA + off*128, fragA + off*128, FH);
        }
        // D-GRU
        mm_bf<<<dim3(3, Dn/128),256,0,stream>>>(msgDm, nullptr, nullptr, nullptr, 256,
            tDWih, D_bih, TGT, Dn, 384, 256, 0, nullptr, nullptr, nullptr, nullptr, nullptr);
        mm_bf<<<dim3(3, Dn/128),256,0,stream>>>(devA, nullptr, nullptr, nullptr, 128,
            tDWhh, D_bhh, Z, Dn, 384, 128, 0, nullptr, nullptr, nullptr, nullptr, nullptr);
        k_gru<<<dim3((Dn*128+255)/256),256,0,stream>>>(TGT, Z, devA, devA, Dn);
        // scatter states
        k_scatter<<<dim3(((size_t)F*128+255)/256),256,0,stream>>>(fragA, cIfrag, state, F, nodes);
        k_scatter<<<dim3((Dn*128+255)/256),256,0,stream>>>(devA, cIdev, state, Dn, nodes);
    }

    // readout
    hipMemsetAsync(pooled, 0, (size_t)S*128*4, stream);
    k_pool_add<<<dim3(((size_t)F*128+255)/256),256,0,stream>>>(fragA, cFsvc, pooled, F, S);
    k_pool_div<<<dim3((S*128+255)/256),256,0,stream>>>(pooled, cLen, S);
    k_mm<<<dim3(256/128, S/128),256,0,stream>>>(pooled, 128, Wl1, 256, bl1, TGT, S, 256, 128, 1, 1.f, 0);
    k_mm<<<dim3(256/128, S/128),256,0,stream>>>(TGT, 256, Wl2, 256, bl2, Z, S, 256, 256, 1, 1.f, 0);
    k_dot_out<<<dim3(S),256,0,stream>>>(Z, Wl3, bl3, outp, 0);
    k_mm<<<dim3(256/128, S/128),256,0,stream>>>(h_srv, 128, Wt1, 256, bt1, TGT, S, 256, 128, 1, 1.f, 0);
    k_mm<<<dim3(256/128, S/128),256,0,stream>>>(TGT, 256, Wt2, 256, bt2, Z, S, 256, 256, 1, 1.f, 0);
    k_dot_out<<<dim3(S),256,0,stream>>>(Z, Wt3, bt3, outp, S);
}

// Round 6
// 1637.584 us; speedup vs baseline: 2.3984x; 1.2066x over previous
//
#include <hip/hip_runtime.h>
#include <hip/hip_bf16.h>

typedef __attribute__((ext_vector_type(8))) short bf16x8;
typedef __attribute__((ext_vector_type(4))) float f32x4;

__device__ __forceinline__ float sigf(float x){ return 1.0f/(1.0f+expf(-x)); }
__device__ __forceinline__ int clampi(int v, int lo, int hi){ return v<lo?lo:(v>hi?hi:v); }
__device__ __forceinline__ unsigned short f2b(float f){
    __hip_bfloat16 h = __float2bfloat16(f);
    return *reinterpret_cast<unsigned short*>(&h);
}

// ---- int64/int32 tolerant index conversion ----
__global__ void k_cvt(const int* __restrict__ src, int* __restrict__ dst, int n,
                      const int* __restrict__ det)
{
    int i = blockIdx.x*blockDim.x + threadIdx.x;
    if (i >= n) return;
    int stride = (det[1] == 0) ? 2 : 1;
    dst[i] = src[(size_t)i*stride];
}

// ---- weight transpose+convert: Wt[n][k] (bf16) <- W[k][n] (f32) ----
__global__ void k_wt(const float* __restrict__ W, unsigned short* __restrict__ Wt,
                     int N, int kshift, int kmask, int total)
{
    int idx = blockIdx.x*blockDim.x + threadIdx.x;
    if (idx >= total) return;
    int n = idx >> kshift, k = idx & kmask;
    Wt[idx] = f2b(W[(size_t)k*N + n]);
}

// ---- concat-head W_src layout: Wc[c][h*256+k] <- W_src[k][h*256+c]  (c in [0,256)) ----
__global__ void k_wtc(const float* __restrict__ W, unsigned short* __restrict__ Wt, int total)
{
    int idx = blockIdx.x*blockDim.x + threadIdx.x;
    if (idx >= total) return;
    int c = idx >> 10, r = idx & 1023;
    int h = r >> 8, k = r & 255;
    Wt[idx] = f2b(W[(size_t)k*1024 + h*256 + c]);
}

// ---------------- init projections ----------------
__global__ void k_proj5(const float* __restrict__ X, const float* __restrict__ W,
                        const float* __restrict__ bias,
                        const int* __restrict__ gidx, const int* __restrict__ sidx,
                        float* __restrict__ out, float* __restrict__ out2, int M, int nrows, int nodes)
{
    int t = blockIdx.x*blockDim.x + threadIdx.x;
    int i = t >> 7, j = t & 127;
    if (i >= M) return;
    int src = gidx ? clampi(gidx[i]-1, 0, nrows-1) : i;
    const float* xp = X + (size_t)src*5;
    float acc = bias[j];
#pragma unroll
    for (int k=0;k<5;k++) acc += xp[k] * W[k*128+j];
    int dr = sidx ? clampi(sidx[i], 0, nodes-1) : i;
    out[(size_t)dr*128 + j] = acc;
    if (out2) out2[(size_t)i*128 + j] = acc;
}

// ---------------- f32 tiled GEMM (readout heads only) ----------------
__launch_bounds__(256)
__global__ void k_mm(const float* __restrict__ A0, int lda,
                     const float* __restrict__ B, int ldb,
                     const float* __restrict__ bias, float* __restrict__ C,
                     int M, int N, int K, int relu, float scale, int accum)
{
    __shared__ float As[16][132];
    __shared__ float Bs[16][132];
    int tid = threadIdx.x;
    int tx = tid & 15, ty = tid >> 4;
    int row0 = blockIdx.y * 128, col0 = blockIdx.x * 128;
    float acc[8][8] = {};
    for (int k0 = 0; k0 < K; k0 += 16){
#pragma unroll
        for (int q = 0; q < 2; ++q){
            int idx = tid + q*256;
            int r = idx >> 2, k4 = (idx & 3) * 4;
            const float* src = A0 + (size_t)(row0+r)*lda + k0 + k4;
            float4 v = *reinterpret_cast<const float4*>(src);
            As[k4+0][r]=v.x; As[k4+1][r]=v.y; As[k4+2][r]=v.z; As[k4+3][r]=v.w;
        }
#pragma unroll
        for (int q = 0; q < 2; ++q){
            int idx = tid + q*256;
            int kb = idx >> 5, n4 = (idx & 31) * 4;
            float4 v = *reinterpret_cast<const float4*>(B + (size_t)(k0+kb)*ldb + col0 + n4);
            *reinterpret_cast<float4*>(&Bs[kb][n4]) = v;
        }
        __syncthreads();
#pragma unroll
        for (int k = 0; k < 16; ++k){
            float a[8], b[8];
            *(float4*)&a[0] = *(const float4*)&As[k][ty*8];
            *(float4*)&a[4] = *(const float4*)&As[k][ty*8+4];
            *(float4*)&b[0] = *(const float4*)&Bs[k][tx*8];
            *(float4*)&b[4] = *(const float4*)&Bs[k][tx*8+4];
#pragma unroll
            for (int i=0;i<8;i++)
#pragma unroll
                for (int j=0;j<8;j++) acc[i][j] += a[i]*b[j];
        }
        __syncthreads();
    }
    float bb[8];
#pragma unroll
    for (int j=0;j<8;j++) bb[j] = bias ? bias[col0+tx*8+j] : 0.f;
#pragma unroll
    for (int i=0;i<8;i++){
        float* cp = C + (size_t)(row0+ty*8+i)*N + col0 + tx*8;
#pragma unroll
        for (int jq=0;jq<2;jq++){
            float4 prev = accum ? *(const float4*)(cp+jq*4) : make_float4(0,0,0,0);
            float o[4];
#pragma unroll
            for (int c=0;c<4;c++){
                float u = acc[i][jq*4+c] + bb[jq*4+c];
                if (relu) u = fmaxf(u,0.f);
                o[c] = (&prev.x)[c] + scale*u;
            }
            *(float4*)(cp+jq*4) = make_float4(o[0],o[1],o[2],o[3]);
        }
    }
}

// ---------------- bf16 MFMA GEMM: C[M,N] = scale*(A(f32->bf16) @ Wt^T) + bias ----------------
// Wt is bf16 [N][K] row-major. Two-half indexed A if A1!=null.
// epi==0: C write.  epi==1: GAT alpha epilogue -> atomicAdd(alphaP).
__launch_bounds__(256)
__global__ void mm_bf(const float* __restrict__ A0, const float* __restrict__ A1,
                      const int* __restrict__ i0, const int* __restrict__ i1, int lda,
                      const unsigned short* __restrict__ Wt,
                      const float* __restrict__ bias, float* __restrict__ C,
                      int M, int N, int K, int epi, float scale,
                      const float* __restrict__ tgtP, const int* __restrict__ rowIdx,
                      const float* __restrict__ attP, const float* __restrict__ bsrcP,
                      float* __restrict__ alphaP)
{
    __shared__ alignas(16) unsigned short As[128*64];
    __shared__ alignas(16) unsigned short Bs[128*64];
    int tid = threadIdx.x;
    int l = tid & 63, w = tid >> 6;
    int wr = w >> 1, wc = w & 1;
    int row0 = blockIdx.y * 128, col0 = blockIdx.x * 128;
    f32x4 acc[4][4];
#pragma unroll
    for (int m=0;m<4;m++)
#pragma unroll
        for (int n=0;n<4;n++) acc[m][n] = (f32x4){0.f,0.f,0.f,0.f};

    for (int k0 = 0; k0 < K; k0 += 64){
#pragma unroll
        for (int q = 0; q < 8; ++q){
            int idx = tid + q*256;
            int r = idx >> 4, c4 = (idx & 15) * 4;
            int kk = k0 + c4;
            const float* src;
            if (A1){
                if (kk < 128){ int ri = i0 ? i0[row0+r] : (row0+r); src = A0 + (size_t)ri*128 + kk; }
                else         { int ri = i1 ? i1[row0+r] : (row0+r); src = A1 + (size_t)ri*128 + (kk-128); }
            } else {
                src = A0 + (size_t)(row0+r)*lda + kk;
            }
            float4 v = *reinterpret_cast<const float4*>(src);
            ushort4 o; o.x=f2b(v.x); o.y=f2b(v.y); o.z=f2b(v.z); o.w=f2b(v.w);
            int csw = c4 ^ ((r & 7) << 3);
            *reinterpret_cast<ushort4*>(&As[r*64 + csw]) = o;
        }
#pragma unroll
        for (int q = 0; q < 4; ++q){
            int idx = tid + q*256;
            int n = idx >> 3, k8 = (idx & 7) * 8;
            uint4 v = *reinterpret_cast<const uint4*>(Wt + (size_t)(col0+n)*K + k0 + k8);
            int ksw = k8 ^ ((n & 7) << 3);
            *reinterpret_cast<uint4*>(&Bs[n*64 + ksw]) = v;
        }
        __syncthreads();
#pragma unroll
        for (int kk = 0; kk < 2; ++kk){
            int ek = kk*32 + (l >> 4) * 8;
            bf16x8 af[4], bf[4];
#pragma unroll
            for (int m=0;m<4;m++){
                int r = wr*64 + m*16 + (l & 15);
                af[m] = *reinterpret_cast<const bf16x8*>(&As[r*64 + (ek ^ ((r & 7) << 3))]);
            }
#pragma unroll
            for (int n=0;n<4;n++){
                int c = wc*64 + n*16 + (l & 15);
                bf[n] = *reinterpret_cast<const bf16x8*>(&Bs[c*64 + (ek ^ ((c & 7) << 3))]);
            }
#pragma unroll
            for (int m=0;m<4;m++)
#pragma unroll
                for (int n=0;n<4;n++)
                    acc[m][n] = __builtin_amdgcn_mfma_f32_16x16x32_bf16(af[m], bf[n], acc[m][n], 0, 0, 0);
        }
        __syncthreads();
    }

    if (epi == 0){
#pragma unroll
        for (int m=0;m<4;m++){
#pragma unroll
            for (int v=0;v<4;v++){
                int row = row0 + wr*64 + m*16 + (l >> 4)*4 + v;
                float* cp = C + (size_t)row*N + col0 + wc*64 + (l & 15);
#pragma unroll
                for (int n=0;n<4;n++){
                    int col = col0 + wc*64 + n*16 + (l & 15);
                    float u = scale*acc[m][n][v] + (bias ? bias[col] : 0.f);
                    cp[n*16] = u;
                }
            }
        }
    } else {
        int h = col0 >> 8;
#pragma unroll
        for (int m=0;m<4;m++){
#pragma unroll
            for (int v=0;v<4;v++){
                int rglob = row0 + wr*64 + m*16 + (l >> 4)*4 + v;
                int dr = rowIdx[rglob];
                const float* tp = tgtP + (size_t)dr*1024 + col0 + wc*64;
                float s = 0.f;
#pragma unroll
                for (int n=0;n<4;n++){
                    int cl = n*16 + (l & 15);
                    int c = col0 + wc*64 + cl;
                    float e = acc[m][n][v] + bsrcP[c] + tp[cl];
                    e = e > 0.f ? e : 0.2f*e;
                    s += e * attP[c];
                }
#pragma unroll
                for (int msk=1; msk<16; msk<<=1) s += __shfl_xor(s, msk);
                if ((l & 15) == 0) atomicAdd(&alphaP[(size_t)rglob*4 + h], s);
            }
        }
    }
}

// ---------------- fused phiC recurrence: 4 services/block, 384 threads ----------------
__launch_bounds__(384)
__global__ void k_recur(float* __restrict__ h_srv, const float* __restrict__ giF,
                        const float* __restrict__ Whh, const float* __restrict__ bhh,
                        const int* __restrict__ inv, float* __restrict__ out_f,
                        int S, int L, int F)
{
    __shared__ float hs[4][128];
    __shared__ float ghs[4][384];
    __shared__ int fLoc[4];
    int tid = threadIdx.x;
    int s0 = blockIdx.x * 4;
    for (int u = tid; u < 512; u += 384){ int s=u>>7,k=u&127; hs[s][k] = h_srv[(size_t)(s0+s)*128+k]; }
    float bb = bhh[tid];
    for (int t=0;t<L;++t){
        if (tid < 4) fLoc[tid] = inv[(size_t)(s0+tid)*L + t];
        __syncthreads();
        float a[4] = {bb,bb,bb,bb};
        for (int k4=0;k4<128;k4+=4){
            float4 hv[4];
#pragma unroll
            for (int s=0;s<4;s++) hv[s] = *(const float4*)&hs[s][k4];
#pragma unroll
            for (int kk=0;kk<4;kk++){
                float wv = Whh[(size_t)(k4+kk)*384 + tid];
#pragma unroll
                for (int s=0;s<4;s++) a[s] += (&hv[s].x)[kk] * wv;
            }
        }
#pragma unroll
        for (int s=0;s<4;s++) ghs[s][tid] = a[s];
        __syncthreads();
        for (int u = tid; u < 512; u += 384){
            int s=u>>7, k=u&127; int f = fLoc[s];
            if (f >= 0 && f < F){
                const float* gp = giF + (size_t)f*384;
                float r  = sigf(gp[k]     + ghs[s][k]);
                float zz = sigf(gp[128+k] + ghs[s][128+k]);
                float n  = tanhf(gp[256+k] + r*ghs[s][256+k]);
                float hn = (1.f-zz)*n + zz*hs[s][k];
                hs[s][k] = hn;
                out_f[(size_t)f*128+k] = hn;
            }
        }
        __syncthreads();
    }
    for (int u = tid; u < 512; u += 384){ int s=u>>7,k=u&127; h_srv[(size_t)(s0+s)*128+k] = hs[s][k]; }
}

// ---------------- GRU pointwise with state write-through ----------------
__global__ void k_gru(const float* __restrict__ gi, const float* __restrict__ gh,
                      const float* __restrict__ hin, float* __restrict__ hout,
                      float* __restrict__ state, const int* __restrict__ sidx,
                      int M, int nodes)
{
    int idx = blockIdx.x*blockDim.x + threadIdx.x;
    int i = idx >> 7, j = idx & 127;
    if (i >= M) return;
    size_t g = (size_t)i*384;
    float r = sigf(gi[g+j]     + gh[g+j]);
    float z = sigf(gi[g+128+j] + gh[g+128+j]);
    float n = tanhf(gi[g+256+j] + r*gh[g+256+j]);
    float hv = hin[(size_t)i*128+j];
    float hn = (1.f-z)*n + z*hv;
    hout[(size_t)i*128+j] = hn;
    if (state) state[(size_t)clampi(sidx[i],0,nodes-1)*128 + j] = hn;
}

// ---------------- per-device softmax + weighted [out_f|fragOld] sum ----------------
__global__ void k_attn_z(const float* __restrict__ out_f, const float* __restrict__ fragOld,
                         const float* __restrict__ alpha,
                         const int* __restrict__ list, const int* __restrict__ offs,
                         float* __restrict__ z, float* __restrict__ sa, int Dn, int F)
{
    int d = blockIdx.x;
    int tid = threadIdx.x;
    int h = tid >> 6, lane = tid & 63;
    int beg = offs[d], end = offs[d+1];
    if (beg < 0) beg = 0; if (end > F) end = F; if (end < beg) end = beg;
    float amax = -3.4e38f;
    for (int i=beg;i<end;i++) amax = fmaxf(amax, alpha[(size_t)list[i]*4+h]);
    float wsum = 0.f;
    for (int i=beg;i<end;i++) wsum += expf(alpha[(size_t)list[i]*4+h]-amax);
    float iws = 1.f/(wsum + 1e-16f);
    float acc[4] = {0,0,0,0};
    for (int i=beg;i<end;i++){
        int f = list[i];
        float a = expf(alpha[(size_t)f*4+h]-amax)*iws;
#pragma unroll
        for (int q=0;q<4;q++){
            int c = lane + q*64;
            float v = (c < 128) ? out_f[(size_t)f*128 + c] : fragOld[(size_t)f*128 + c - 128];
            acc[q] += a * v;
        }
    }
#pragma unroll
    for (int q=0;q<4;q++) z[(size_t)d*1024 + h*256 + lane + q*64] = acc[q];
    if (lane == 0) sa[d*4+h] = (end>beg) ? wsum*iws : 0.f;
}

__global__ void k_msgd_fix(float* __restrict__ msgD, const float* __restrict__ sa,
                           const float* __restrict__ bsrc, const float* __restrict__ batt, int Dn)
{
    int idx = blockIdx.x*blockDim.x + threadIdx.x;
    int d = idx >> 8, c = idx & 255;
    if (d >= Dn) return;
    float v = batt[c];
#pragma unroll
    for (int h=0;h<4;h++) v += 0.25f * sa[d*4+h] * bsrc[h*256+c];
    msgD[(size_t)d*256 + c] += v;
}

__global__ void k_count(const int* __restrict__ row, int* __restrict__ counts, int F, int Dn)
{ int f = blockIdx.x*blockDim.x + threadIdx.x; if (f < F) atomicAdd(&counts[clampi(row[f],0,Dn-1)], 1); }

__global__ void k_scan(const int* __restrict__ counts, int* __restrict__ offs, int D)
{
    __shared__ int part[257];
    int tid = threadIdx.x;
    int per = (D + 255) / 256;
    int s = 0;
    for (int i=0;i<per;i++){ int idx = tid*per+i; if (idx < D) s += counts[idx]; }
    part[tid] = s;
    __syncthreads();
    if (tid == 0){
        int acc = 0;
        for (int i=0;i<256;i++){ int v = part[i]; part[i] = acc; acc += v; }
        part[256] = acc;
    }
    __syncthreads();
    int acc = part[tid];
    for (int i=0;i<per;i++){ int idx = tid*per+i; if (idx < D){ offs[idx] = acc; acc += counts[idx]; } }
    if (tid == 0) offs[D] = part[256];
}

__global__ void k_fill(const int* __restrict__ row, const int* __restrict__ offs,
                       int* __restrict__ cursor, int* __restrict__ list, int F, int Dn)
{
    int f = blockIdx.x*blockDim.x + threadIdx.x;
    if (f >= F) return;
    int r = clampi(row[f],0,Dn-1);
    int p = atomicAdd(&cursor[r], 1);
    int pos = offs[r]+p;
    if (pos >= 0 && pos < F) list[pos] = f;
}

__global__ void k_build_inv(const int* __restrict__ fs, const int* __restrict__ fp,
                            int* __restrict__ inv, int F, int L, int S)
{
    int f = blockIdx.x*blockDim.x + threadIdx.x;
    if (f >= F) return;
    inv[clampi(fs[f],0,S-1)*L + clampi(fp[f],0,L-1)] = f;
}

__global__ void k_pool_add(const float* __restrict__ frag, const int* __restrict__ fs,
                           float* __restrict__ pooled, int F, int S)
{
    int t = blockIdx.x*blockDim.x + threadIdx.x;
    int i = t >> 7, j = t & 127;
    if (i >= F) return;
    atomicAdd(&pooled[(size_t)clampi(fs[i],0,S-1)*128 + j], frag[(size_t)i*128 + j]);
}

__global__ void k_pool_div(float* __restrict__ pooled, const int* __restrict__ lengths, int S)
{
    int t = blockIdx.x*blockDim.x + threadIdx.x;
    int i = t >> 7, j = t & 127;
    if (i >= S) return;
    int l = lengths[i]; if (l < 1) l = 1;
    pooled[(size_t)i*128 + j] /= (float)l;
}

__global__ void k_dot_out(const float* __restrict__ H, const float* __restrict__ W3,
                          const float* __restrict__ b3, float* __restrict__ outv, int off)
{
    __shared__ float red[256];
    int s = blockIdx.x, tid = threadIdx.x;
    red[tid] = H[(size_t)s*256 + tid] * W3[tid];
    __syncthreads();
    for (int st=128; st; st>>=1){ if (tid < st) red[tid] += red[tid+st]; __syncthreads(); }
    if (tid == 0) outv[off + s] = red[0] + b3[0];
}

// =====================================================================================
extern "C" void kernel_launch(void* const* d_in, const int* in_sizes, int n_in,
                              void* d_out, int out_size, void* d_ws, size_t ws_size,
                              hipStream_t stream)
{
    (void)n_in; (void)out_size; (void)ws_size;
    const float* realnode = (const float*)d_in[0];
    const float* arr      = (const float*)d_in[1];
    const int* r_exe   = (const int*)d_in[2];
    const int* r_idev  = (const int*)d_in[3];
    const int* r_ifrag = (const int*)d_in[4];
    const int* r_fdn   = (const int*)d_in[5];
    const int* r_fdr   = (const int*)d_in[6];
    const int* r_len   = (const int*)d_in[7];
    const int* r_fsvc  = (const int*)d_in[8];
    const int* r_fpos  = (const int*)d_in[9];
    const float *W_dev=(const float*)d_in[10], *b_dev=(const float*)d_in[11];
    const float *W_frg=(const float*)d_in[12], *b_frg=(const float*)d_in[13];
    const float *W_srv=(const float*)d_in[14], *b_srv=(const float*)d_in[15];
    const float *C_Wih=(const float*)d_in[16], *C_Whh=(const float*)d_in[17], *C_bih=(const float*)d_in[18], *C_bhh=(const float*)d_in[19];
    const float *F_Wih=(const float*)d_in[20], *F_Whh=(const float*)d_in[21], *F_bih=(const float*)d_in[22], *F_bhh=(const float*)d_in[23];
    const float *D_Wih=(const float*)d_in[24], *D_Whh=(const float*)d_in[25], *D_bih=(const float*)d_in[26], *D_bhh=(const float*)d_in[27];
    const float *W_src=(const float*)d_in[28], *b_src=(const float*)d_in[29];
    const float *W_tgt=(const float*)d_in[30], *b_tgt=(const float*)d_in[31];
    const float *att=(const float*)d_in[32], *bias_att=(const float*)d_in[33];
    const float *Wt1=(const float*)d_in[34], *bt1=(const float*)d_in[35], *Wt2=(const float*)d_in[36], *bt2=(const float*)d_in[37], *Wt3=(const float*)d_in[38], *bt3=(const float*)d_in[39];
    const float *Wl1=(const float*)d_in[40], *bl1=(const float*)d_in[41], *Wl2=(const float*)d_in[42], *bl2=(const float*)d_in[43], *Wl3=(const float*)d_in[44], *bl3=(const float*)d_in[45];
    float* outp = (float*)d_out;

    const int S  = in_sizes[7];
    const int Dn = in_sizes[3];
    const int F  = in_sizes[4];
    const int L  = in_sizes[2] / (2*S);
    const int nreal = in_sizes[0]/5;
    const int nodes = nreal + 1;
    const int NIT = 3;
    const int FH = F/2;

    char* wp = (char*)d_ws;
    auto alloc = [&](size_t nelem)->float*{
        float* p = (float*)wp;
        wp += ((nelem*4 + 255)/256)*256;
        return p;
    };
    float* state  = alloc((size_t)nodes*128);
    float* h_srv  = alloc((size_t)S*128);
    float* out_f  = alloc((size_t)F*128);
    float* fragA  = alloc((size_t)F*128);
    float* devA   = alloc((size_t)Dn*128);
    float* alphaB = alloc((size_t)F*4);
    float* msgDm  = alloc((size_t)Dn*256);
    float* saB    = alloc((size_t)Dn*4);
    float* giF    = alloc((size_t)F*384);
    float* TGT    = alloc((size_t)Dn*1024);
    float* Z      = alloc((size_t)Dn*1024);
    float* pooled = alloc((size_t)S*128);
    unsigned short* tCWih  = (unsigned short*)alloc(384*256/2);
    unsigned short* tFWih  = (unsigned short*)alloc(384*256/2);
    unsigned short* tFWhh  = (unsigned short*)alloc(384*128/2);
    unsigned short* tDWih  = (unsigned short*)alloc(384*256/2);
    unsigned short* tDWhh  = (unsigned short*)alloc(384*128/2);
    unsigned short* tWtgt  = (unsigned short*)alloc(1024*128/2);
    unsigned short* tWsrc  = (unsigned short*)alloc(1024*256/2);
    unsigned short* tWsrcC = (unsigned short*)alloc(256*1024/2);
    int* cExe   = (int*)alloc((size_t)S*2*L);
    int* cIdev  = (int*)alloc((size_t)Dn);
    int* cIfrag = (int*)alloc((size_t)F);
    int* cFdn   = (int*)alloc((size_t)F);
    int* cFdr   = (int*)alloc((size_t)F);
    int* cLen   = (int*)alloc((size_t)S);
    int* cFsvc  = (int*)alloc((size_t)F);
    int* cFpos  = (int*)alloc((size_t)F);
    int* inv    = (int*)alloc((size_t)S*L);
    int* counts = (int*)alloc((size_t)Dn);
    int* offs   = (int*)alloc((size_t)Dn+1);
    int* cursor = (int*)alloc((size_t)Dn);
    int* list   = (int*)alloc((size_t)F);

    const int* det = r_idev;
    auto cvt = [&](const int* src, int* dst, int n){
        k_cvt<<<dim3((n+255)/256),256,0,stream>>>(src, dst, n, det);
    };
    cvt(r_exe,  cExe,  S*2*L);
    cvt(r_idev, cIdev, Dn);
    cvt(r_ifrag,cIfrag,F);
    cvt(r_fdn,  cFdn,  F);
    cvt(r_fdr,  cFdr,  F);
    cvt(r_len,  cLen,  S);
    cvt(r_fsvc, cFsvc, F);
    cvt(r_fpos, cFpos, F);

    k_wt<<<dim3((98304+255)/256),256,0,stream>>>(C_Wih, tCWih, 384, 8, 255, 98304);
    k_wt<<<dim3((98304+255)/256),256,0,stream>>>(F_Wih, tFWih, 384, 8, 255, 98304);
    k_wt<<<dim3((49152+255)/256),256,0,stream>>>(F_Whh, tFWhh, 384, 7, 127, 49152);
    k_wt<<<dim3((98304+255)/256),256,0,stream>>>(D_Wih, tDWih, 384, 8, 255, 98304);
    k_wt<<<dim3((49152+255)/256),256,0,stream>>>(D_Whh, tDWhh, 384, 7, 127, 49152);
    k_wt<<<dim3((131072+255)/256),256,0,stream>>>(W_tgt, tWtgt, 1024, 7, 127, 131072);
    k_wt<<<dim3((262144+255)/256),256,0,stream>>>(W_src, tWsrc, 1024, 8, 255, 262144);
    k_wtc<<<dim3((262144+255)/256),256,0,stream>>>(W_src, tWsrcC, 262144);

    hipMemsetAsync(state, 0, (size_t)nodes*128*4, stream);
    hipMemsetAsync(inv, 0xFF, (size_t)S*L*4, stream);
    hipMemsetAsync(counts, 0, (size_t)Dn*4, stream);
    hipMemsetAsync(cursor, 0, (size_t)Dn*4, stream);

    k_proj5<<<dim3((Dn*128+255)/256),256,0,stream>>>(realnode, W_dev, b_dev, cIdev, cIdev, state, devA, Dn, nreal, nodes);
    k_proj5<<<dim3(((size_t)F*128+255)/256),256,0,stream>>>(realnode, W_frg, b_frg, cIfrag, cIfrag, state, fragA, F, nreal, nodes);
    k_proj5<<<dim3((S*128+255)/256),256,0,stream>>>(arr, W_srv, b_srv, nullptr, nullptr, h_srv, nullptr, S, S, nodes);
    k_build_inv<<<dim3((F+255)/256),256,0,stream>>>(cFsvc, cFpos, inv, F, L, S);
    k_count<<<dim3((F+255)/256),256,0,stream>>>(cFdr, counts, F, Dn);
    k_scan<<<1,256,0,stream>>>(counts, offs, Dn);
    k_fill<<<dim3((F+255)/256),256,0,stream>>>(cFdr, offs, cursor, list, F, Dn);

    for (int it=0; it<NIT; ++it){
        // phiC: batched gi (MFMA) + fused recurrence
        mm_bf<<<dim3(3, F/128),256,0,stream>>>(state, state, cIfrag, cFdn, 0,
            tCWih, C_bih, giF, F, 384, 256, 0, 1.f, nullptr, nullptr, nullptr, nullptr, nullptr);
        k_recur<<<dim3(S/4),384,0,stream>>>(h_srv, giF, C_Whh, C_bhh, inv, out_f, S, L, F);
        // attention
        mm_bf<<<dim3(8, Dn/128),256,0,stream>>>(devA, nullptr, nullptr, nullptr, 128,
            tWtgt, b_tgt, TGT, Dn, 1024, 128, 0, 1.f, nullptr, nullptr, nullptr, nullptr, nullptr);
        hipMemsetAsync(alphaB, 0, (size_t)F*4*4, stream);
        mm_bf<<<dim3(8, F/128),256,0,stream>>>(out_f, fragA, nullptr, nullptr, 0,
            tWsrc, nullptr, nullptr, F, 1024, 256, 1, 1.f, TGT, cFdr, att, b_src, alphaB);
        k_attn_z<<<dim3(Dn),256,0,stream>>>(out_f, fragA, alphaB, list, offs, Z, saB, Dn, F);
        // msgD = 0.25 * Z[Dn,1024] @ Wcat[1024,256]  (single MFMA GEMM)
        mm_bf<<<dim3(2, Dn/128),256,0,stream>>>(Z, nullptr, nullptr, nullptr, 1024,
            tWsrcC, nullptr, msgDm, Dn, 256, 1024, 0, 0.25f, nullptr, nullptr, nullptr, nullptr, nullptr);
        k_msgd_fix<<<dim3((Dn*256+255)/256),256,0,stream>>>(msgDm, saB, b_src, bias_att, Dn);
        // F-GRU chunked 2x (in-place, write-through to state)
        for (int c=0;c<2;c++){
            size_t off = (size_t)c*FH;
            mm_bf<<<dim3(3, FH/128),256,0,stream>>>(out_f + off*128, state, nullptr, cFdn + off, 0,
                tFWih, F_bih, TGT, FH, 384, 256, 0, 1.f, nullptr, nullptr, nullptr, nullptr, nullptr);
            mm_bf<<<dim3(3, FH/128),256,0,stream>>>(fragA + off*128, nullptr, nullptr, nullptr, 128,
                tFWhh, F_bhh, Z, FH, 384, 128, 0, 1.f, nullptr, nullptr, nullptr, nullptr, nullptr);
            k_gru<<<dim3(((size_t)FH*128+255)/256),256,0,stream>>>(TGT, Z, fragA + off*128, fragA + off*128,
                state, cIfrag + off, FH, nodes);
        }
        // D-GRU (in-place, write-through to state)
        mm_bf<<<dim3(3, Dn/128),256,0,stream>>>(msgDm, nullptr, nullptr, nullptr, 256,
            tDWih, D_bih, TGT, Dn, 384, 256, 0, 1.f, nullptr, nullptr, nullptr, nullptr, nullptr);
        mm_bf<<<dim3(3, Dn/128),256,0,stream>>>(devA, nullptr, nullptr, nullptr, 128,
            tDWhh, D_bhh, Z, Dn, 384, 128, 0, 1.f, nullptr, nullptr, nullptr, nullptr, nullptr);
        k_gru<<<dim3((Dn*128+255)/256),256,0,stream>>>(TGT, Z, devA, devA, state, cIdev, Dn, nodes);
    }

    // readout
    hipMemsetAsync(pooled, 0, (size_t)S*128*4, stream);
    k_pool_add<<<dim3(((size_t)F*128+255)/256),256,0,stream>>>(fragA, cFsvc, pooled, F, S);
    k_pool_div<<<dim3((S*128+255)/256),256,0,stream>>>(pooled, cLen, S);
    k_mm<<<dim3(256/128, S/128),256,0,stream>>>(pooled, 128, Wl1, 256, bl1, TGT, S, 256, 128, 1, 1.f, 0);
    k_mm<<<dim3(256/128, S/128),256,0,stream>>>(TGT, 256, Wl2, 256, bl2, Z, S, 256, 256, 1, 1.f, 0);
    k_dot_out<<<dim3(S),256,0,stream>>>(Z, Wl3, bl3, outp, 0);
    k_mm<<<dim3(256/128, S/128),256,0,stream>>>(h_srv, 128, Wt1, 256, bt1, TGT, S, 256, 128, 1, 1.f, 0);
    k_mm<<<dim3(256/128, S/128),256,0,stream>>>(TGT, 256, Wt2, 256, bt2, Z, S, 256, 256, 1, 1.f, 0);
    k_dot_out<<<dim3(S),256,0,stream>>>(Z, Wt3, bt3, outp, S);
}

// Round 7
// 1518.456 us; speedup vs baseline: 2.5866x; 1.0785x over previous
//
#include <hip/hip_runtime.h>
#include <hip/hip_bf16.h>

typedef __attribute__((ext_vector_type(8))) short bf16x8;
typedef __attribute__((ext_vector_type(4))) float f32x4;

__device__ __forceinline__ float sigf(float x){ return 1.0f/(1.0f+expf(-x)); }
__device__ __forceinline__ int clampi(int v, int lo, int hi){ return v<lo?lo:(v>hi?hi:v); }
__device__ __forceinline__ unsigned short f2b(float f){
    __hip_bfloat16 h = __float2bfloat16(f);
    return *reinterpret_cast<unsigned short*>(&h);
}
__device__ __forceinline__ float us2f(unsigned short u){ return __uint_as_float(((unsigned)u)<<16); }

// ---- int64/int32 tolerant index conversion ----
__global__ void k_cvt(const int* __restrict__ src, int* __restrict__ dst, int n,
                      const int* __restrict__ det)
{
    int i = blockIdx.x*blockDim.x + threadIdx.x;
    if (i >= n) return;
    int stride = (det[1] == 0) ? 2 : 1;
    dst[i] = src[(size_t)i*stride];
}

// ---- weight transpose+convert: Wt[n][k] (bf16) <- W[k][n] (f32) ----
__global__ void k_wt(const float* __restrict__ W, unsigned short* __restrict__ Wt,
                     int N, int kshift, int kmask, int total)
{
    int idx = blockIdx.x*blockDim.x + threadIdx.x;
    if (idx >= total) return;
    int n = idx >> kshift, k = idx & kmask;
    Wt[idx] = f2b(W[(size_t)k*N + n]);
}

// ---- split transpose+convert: Whi/Wlo[n][k] <- W[k][n], lo = residual ----
__global__ void k_wt2(const float* __restrict__ W, unsigned short* __restrict__ Whi,
                      unsigned short* __restrict__ Wlo, int N, int kshift, int kmask, int total)
{
    int idx = blockIdx.x*blockDim.x + threadIdx.x;
    if (idx >= total) return;
    int n = idx >> kshift, k = idx & kmask;
    float v = W[(size_t)k*N + n];
    unsigned short hi = f2b(v);
    Whi[idx] = hi;
    Wlo[idx] = f2b(v - us2f(hi));
}

// ---- concat-head W_src layout: Wc[c][h*256+k] <- W_src[k][h*256+c] ----
__global__ void k_wtc(const float* __restrict__ W, unsigned short* __restrict__ Wt, int total)
{
    int idx = blockIdx.x*blockDim.x + threadIdx.x;
    if (idx >= total) return;
    int c = idx >> 10, r = idx & 1023;
    int h = r >> 8, k = r & 255;
    Wt[idx] = f2b(W[(size_t)k*1024 + h*256 + c]);
}

// ---------------- init projections ----------------
__global__ void k_proj5(const float* __restrict__ X, const float* __restrict__ W,
                        const float* __restrict__ bias,
                        const int* __restrict__ gidx, const int* __restrict__ sidx,
                        float* __restrict__ out, float* __restrict__ out2, int M, int nrows, int nodes)
{
    int t = blockIdx.x*blockDim.x + threadIdx.x;
    int i = t >> 7, j = t & 127;
    if (i >= M) return;
    int src = gidx ? clampi(gidx[i]-1, 0, nrows-1) : i;
    const float* xp = X + (size_t)src*5;
    float acc = bias[j];
#pragma unroll
    for (int k=0;k<5;k++) acc += xp[k] * W[k*128+j];
    int dr = sidx ? clampi(sidx[i], 0, nodes-1) : i;
    out[(size_t)dr*128 + j] = acc;
    if (out2) out2[(size_t)i*128 + j] = acc;
}

// ---------------- f32 tiled GEMM (readout heads only) ----------------
__launch_bounds__(256)
__global__ void k_mm(const float* __restrict__ A0, int lda,
                     const float* __restrict__ B, int ldb,
                     const float* __restrict__ bias, float* __restrict__ C,
                     int M, int N, int K, int relu, float scale, int accum)
{
    __shared__ float As[16][132];
    __shared__ float Bs[16][132];
    int tid = threadIdx.x;
    int tx = tid & 15, ty = tid >> 4;
    int row0 = blockIdx.y * 128, col0 = blockIdx.x * 128;
    float acc[8][8] = {};
    for (int k0 = 0; k0 < K; k0 += 16){
#pragma unroll
        for (int q = 0; q < 2; ++q){
            int idx = tid + q*256;
            int r = idx >> 2, k4 = (idx & 3) * 4;
            const float* src = A0 + (size_t)(row0+r)*lda + k0 + k4;
            float4 v = *reinterpret_cast<const float4*>(src);
            As[k4+0][r]=v.x; As[k4+1][r]=v.y; As[k4+2][r]=v.z; As[k4+3][r]=v.w;
        }
#pragma unroll
        for (int q = 0; q < 2; ++q){
            int idx = tid + q*256;
            int kb = idx >> 5, n4 = (idx & 31) * 4;
            float4 v = *reinterpret_cast<const float4*>(B + (size_t)(k0+kb)*ldb + col0 + n4);
            *reinterpret_cast<float4*>(&Bs[kb][n4]) = v;
        }
        __syncthreads();
#pragma unroll
        for (int k = 0; k < 16; ++k){
            float a[8], b[8];
            *(float4*)&a[0] = *(const float4*)&As[k][ty*8];
            *(float4*)&a[4] = *(const float4*)&As[k][ty*8+4];
            *(float4*)&b[0] = *(const float4*)&Bs[k][tx*8];
            *(float4*)&b[4] = *(const float4*)&Bs[k][tx*8+4];
#pragma unroll
            for (int i=0;i<8;i++)
#pragma unroll
                for (int j=0;j<8;j++) acc[i][j] += a[i]*b[j];
        }
        __syncthreads();
    }
    float bb[8];
#pragma unroll
    for (int j=0;j<8;j++) bb[j] = bias ? bias[col0+tx*8+j] : 0.f;
#pragma unroll
    for (int i=0;i<8;i++){
        float* cp = C + (size_t)(row0+ty*8+i)*N + col0 + tx*8;
#pragma unroll
        for (int jq=0;jq<2;jq++){
            float4 prev = accum ? *(const float4*)(cp+jq*4) : make_float4(0,0,0,0);
            float o[4];
#pragma unroll
            for (int c=0;c<4;c++){
                float u = acc[i][jq*4+c] + bb[jq*4+c];
                if (relu) u = fmaxf(u,0.f);
                o[c] = (&prev.x)[c] + scale*u;
            }
            *(float4*)(cp+jq*4) = make_float4(o[0],o[1],o[2],o[3]);
        }
    }
}

// ---------------- bf16 MFMA GEMM: C[M,N] = scale*(A(f32->bf16) @ Wt^T) + bias ----------------
__launch_bounds__(256)
__global__ void mm_bf(const float* __restrict__ A0, const float* __restrict__ A1,
                      const int* __restrict__ i0, const int* __restrict__ i1, int lda,
                      const unsigned short* __restrict__ Wt,
                      const float* __restrict__ bias, float* __restrict__ C,
                      int M, int N, int K, int epi, float scale,
                      const float* __restrict__ tgtP, const int* __restrict__ rowIdx,
                      const float* __restrict__ attP, const float* __restrict__ bsrcP,
                      float* __restrict__ alphaP)
{
    __shared__ alignas(16) unsigned short As[128*64];
    __shared__ alignas(16) unsigned short Bs[128*64];
    int tid = threadIdx.x;
    int l = tid & 63, w = tid >> 6;
    int wr = w >> 1, wc = w & 1;
    int row0 = blockIdx.y * 128, col0 = blockIdx.x * 128;
    f32x4 acc[4][4];
#pragma unroll
    for (int m=0;m<4;m++)
#pragma unroll
        for (int n=0;n<4;n++) acc[m][n] = (f32x4){0.f,0.f,0.f,0.f};

    for (int k0 = 0; k0 < K; k0 += 64){
#pragma unroll
        for (int q = 0; q < 8; ++q){
            int idx = tid + q*256;
            int r = idx >> 4, c4 = (idx & 15) * 4;
            int kk = k0 + c4;
            const float* src;
            if (A1){
                if (kk < 128){ int ri = i0 ? i0[row0+r] : (row0+r); src = A0 + (size_t)ri*128 + kk; }
                else         { int ri = i1 ? i1[row0+r] : (row0+r); src = A1 + (size_t)ri*128 + (kk-128); }
            } else {
                src = A0 + (size_t)(row0+r)*lda + kk;
            }
            float4 v = *reinterpret_cast<const float4*>(src);
            ushort4 o; o.x=f2b(v.x); o.y=f2b(v.y); o.z=f2b(v.z); o.w=f2b(v.w);
            int csw = c4 ^ ((r & 7) << 3);
            *reinterpret_cast<ushort4*>(&As[r*64 + csw]) = o;
        }
#pragma unroll
        for (int q = 0; q < 4; ++q){
            int idx = tid + q*256;
            int n = idx >> 3, k8 = (idx & 7) * 8;
            uint4 v = *reinterpret_cast<const uint4*>(Wt + (size_t)(col0+n)*K + k0 + k8);
            int ksw = k8 ^ ((n & 7) << 3);
            *reinterpret_cast<uint4*>(&Bs[n*64 + ksw]) = v;
        }
        __syncthreads();
#pragma unroll
        for (int kk = 0; kk < 2; ++kk){
            int ek = kk*32 + (l >> 4) * 8;
            bf16x8 af[4], bf[4];
#pragma unroll
            for (int m=0;m<4;m++){
                int r = wr*64 + m*16 + (l & 15);
                af[m] = *reinterpret_cast<const bf16x8*>(&As[r*64 + (ek ^ ((r & 7) << 3))]);
            }
#pragma unroll
            for (int n=0;n<4;n++){
                int c = wc*64 + n*16 + (l & 15);
                bf[n] = *reinterpret_cast<const bf16x8*>(&Bs[c*64 + (ek ^ ((c & 7) << 3))]);
            }
#pragma unroll
            for (int m=0;m<4;m++)
#pragma unroll
                for (int n=0;n<4;n++)
                    acc[m][n] = __builtin_amdgcn_mfma_f32_16x16x32_bf16(af[m], bf[n], acc[m][n], 0, 0, 0);
        }
        __syncthreads();
    }

    if (epi == 0){
#pragma unroll
        for (int m=0;m<4;m++){
#pragma unroll
            for (int v=0;v<4;v++){
                int row = row0 + wr*64 + m*16 + (l >> 4)*4 + v;
                float* cp = C + (size_t)row*N + col0 + wc*64 + (l & 15);
#pragma unroll
                for (int n=0;n<4;n++){
                    int col = col0 + wc*64 + n*16 + (l & 15);
                    float u = scale*acc[m][n][v] + (bias ? bias[col] : 0.f);
                    cp[n*16] = u;
                }
            }
        }
    } else {
        int h = col0 >> 8;
#pragma unroll
        for (int m=0;m<4;m++){
#pragma unroll
            for (int v=0;v<4;v++){
                int rglob = row0 + wr*64 + m*16 + (l >> 4)*4 + v;
                int dr = rowIdx[rglob];
                const float* tp = tgtP + (size_t)dr*1024 + col0 + wc*64;
                float s = 0.f;
#pragma unroll
                for (int n=0;n<4;n++){
                    int cl = n*16 + (l & 15);
                    int c = col0 + wc*64 + cl;
                    float e = acc[m][n][v] + bsrcP[c] + tp[cl];
                    e = e > 0.f ? e : 0.2f*e;
                    s += e * attP[c];
                }
#pragma unroll
                for (int msk=1; msk<16; msk<<=1) s += __shfl_xor(s, msk);
                if ((l & 15) == 0) atomicAdd(&alphaP[(size_t)rglob*4 + h], s);
            }
        }
    }
}

// ---------------- fused phiC recurrence: MFMA gh, Whh stationary in registers ----------------
// 16 services/block, 512 threads (8 waves). Wave w owns gh cols [w*48, w*48+48).
// Split bf16: gh = Whi*hhi + Whi*hlo + Wlo*hhi  (f32-grade accuracy).
__launch_bounds__(512)
__global__ void k_recur(float* __restrict__ h_srv, const float* __restrict__ giF,
                        const unsigned short* __restrict__ Whi,
                        const unsigned short* __restrict__ Wlo,
                        const float* __restrict__ bhh,
                        const int* __restrict__ inv, float* __restrict__ out_f,
                        int S, int L, int F)
{
    __shared__ float hs[16][132];
    __shared__ float ghs[16][388];
    __shared__ int fLoc[16];
    int tid = threadIdx.x;
    int l = tid & 63, w = tid >> 6;
    int lane15 = l & 15, lhi = l >> 4;
    int s0 = blockIdx.x * 16;
    for (int u = tid; u < 2048; u += 512){ int s=u>>7,k=u&127; hs[s][k] = h_srv[(size_t)(s0+s)*128+k]; }
    // stationary Whh fragments (B operand: col = lane15, k = ks*32 + lhi*8 + j)
    bf16x8 wHi[3][4], wLo[3][4];
#pragma unroll
    for (int ct=0; ct<3; ++ct){
        int col = w*48 + ct*16 + lane15;
#pragma unroll
        for (int ks=0; ks<4; ++ks){
            size_t off = (size_t)col*128 + ks*32 + lhi*8;
            wHi[ct][ks] = *reinterpret_cast<const bf16x8*>(Whi + off);
            wLo[ct][ks] = *reinterpret_cast<const bf16x8*>(Wlo + off);
        }
    }
    __syncthreads();
    for (int t=0;t<L;++t){
        if (tid < 16) fLoc[tid] = inv[(size_t)(s0+tid)*L + t];
        __syncthreads();
        // A operand from h: row = lane15 (service), k = ks*32 + lhi*8 + j; split hi/lo
        bf16x8 hHi[4], hLo[4];
#pragma unroll
        for (int ks=0; ks<4; ++ks){
            const float* hp = &hs[lane15][ks*32 + lhi*8];
#pragma unroll
            for (int j=0;j<8;j++){
                float v = hp[j];
                unsigned short hi = f2b(v);
                hHi[ks][j] = (short)hi;
                hLo[ks][j] = (short)f2b(v - us2f(hi));
            }
        }
#pragma unroll
        for (int ct=0; ct<3; ++ct){
            f32x4 acc = (f32x4){0.f,0.f,0.f,0.f};
#pragma unroll
            for (int ks=0; ks<4; ++ks){
                acc = __builtin_amdgcn_mfma_f32_16x16x32_bf16(hHi[ks], wHi[ct][ks], acc, 0,0,0);
                acc = __builtin_amdgcn_mfma_f32_16x16x32_bf16(hLo[ks], wHi[ct][ks], acc, 0,0,0);
                acc = __builtin_amdgcn_mfma_f32_16x16x32_bf16(hHi[ks], wLo[ct][ks], acc, 0,0,0);
            }
            int col = w*48 + ct*16 + lane15;
            float bb = bhh[col];
#pragma unroll
            for (int v=0; v<4; ++v){
                ghs[lhi*4 + v][col] = acc[v] + bb;
            }
        }
        __syncthreads();
        for (int u = tid; u < 2048; u += 512){
            int s=u>>7, k=u&127; int f = fLoc[s];
            if (f >= 0 && f < F){
                const float* gp = giF + (size_t)f*384;
                float r  = sigf(gp[k]     + ghs[s][k]);
                float zz = sigf(gp[128+k] + ghs[s][128+k]);
                float n  = tanhf(gp[256+k] + r*ghs[s][256+k]);
                float hn = (1.f-zz)*n + zz*hs[s][k];
                hs[s][k] = hn;
                out_f[(size_t)f*128+k] = hn;
            }
        }
        __syncthreads();
    }
    for (int u = tid; u < 2048; u += 512){ int s=u>>7,k=u&127; h_srv[(size_t)(s0+s)*128+k] = hs[s][k]; }
}

// ---------------- GRU pointwise with state write-through ----------------
__global__ void k_gru(const float* __restrict__ gi, const float* __restrict__ gh,
                      const float* __restrict__ hin, float* __restrict__ hout,
                      float* __restrict__ state, const int* __restrict__ sidx,
                      int M, int nodes)
{
    int idx = blockIdx.x*blockDim.x + threadIdx.x;
    int i = idx >> 7, j = idx & 127;
    if (i >= M) return;
    size_t g = (size_t)i*384;
    float r = sigf(gi[g+j]     + gh[g+j]);
    float z = sigf(gi[g+128+j] + gh[g+128+j]);
    float n = tanhf(gi[g+256+j] + r*gh[g+256+j]);
    float hv = hin[(size_t)i*128+j];
    float hn = (1.f-z)*n + z*hv;
    hout[(size_t)i*128+j] = hn;
    if (state) state[(size_t)clampi(sidx[i],0,nodes-1)*128 + j] = hn;
}

// ---------------- per-device softmax + weighted [out_f|fragOld] sum ----------------
__global__ void k_attn_z(const float* __restrict__ out_f, const float* __restrict__ fragOld,
                         const float* __restrict__ alpha,
                         const int* __restrict__ list, const int* __restrict__ offs,
                         float* __restrict__ z, float* __restrict__ sa, int Dn, int F)
{
    int d = blockIdx.x;
    int tid = threadIdx.x;
    int h = tid >> 6, lane = tid & 63;
    int beg = offs[d], end = offs[d+1];
    if (beg < 0) beg = 0; if (end > F) end = F; if (end < beg) end = beg;
    float amax = -3.4e38f;
    for (int i=beg;i<end;i++) amax = fmaxf(amax, alpha[(size_t)list[i]*4+h]);
    float wsum = 0.f;
    for (int i=beg;i<end;i++) wsum += expf(alpha[(size_t)list[i]*4+h]-amax);
    float iws = 1.f/(wsum + 1e-16f);
    float acc[4] = {0,0,0,0};
    for (int i=beg;i<end;i++){
        int f = list[i];
        float a = expf(alpha[(size_t)f*4+h]-amax)*iws;
#pragma unroll
        for (int q=0;q<4;q++){
            int c = lane + q*64;
            float v = (c < 128) ? out_f[(size_t)f*128 + c] : fragOld[(size_t)f*128 + c - 128];
            acc[q] += a * v;
        }
    }
#pragma unroll
    for (int q=0;q<4;q++) z[(size_t)d*1024 + h*256 + lane + q*64] = acc[q];
    if (lane == 0) sa[d*4+h] = (end>beg) ? wsum*iws : 0.f;
}

__global__ void k_msgd_fix(float* __restrict__ msgD, const float* __restrict__ sa,
                           const float* __restrict__ bsrc, const float* __restrict__ batt, int Dn)
{
    int idx = blockIdx.x*blockDim.x + threadIdx.x;
    int d = idx >> 8, c = idx & 255;
    if (d >= Dn) return;
    float v = batt[c];
#pragma unroll
    for (int h=0;h<4;h++) v += 0.25f * sa[d*4+h] * bsrc[h*256+c];
    msgD[(size_t)d*256 + c] += v;
}

__global__ void k_count(const int* __restrict__ row, int* __restrict__ counts, int F, int Dn)
{ int f = blockIdx.x*blockDim.x + threadIdx.x; if (f < F) atomicAdd(&counts[clampi(row[f],0,Dn-1)], 1); }

__global__ void k_scan(const int* __restrict__ counts, int* __restrict__ offs, int D)
{
    __shared__ int part[257];
    int tid = threadIdx.x;
    int per = (D + 255) / 256;
    int s = 0;
    for (int i=0;i<per;i++){ int idx = tid*per+i; if (idx < D) s += counts[idx]; }
    part[tid] = s;
    __syncthreads();
    if (tid == 0){
        int acc = 0;
        for (int i=0;i<256;i++){ int v = part[i]; part[i] = acc; acc += v; }
        part[256] = acc;
    }
    __syncthreads();
    int acc = part[tid];
    for (int i=0;i<per;i++){ int idx = tid*per+i; if (idx < D){ offs[idx] = acc; acc += counts[idx]; } }
    if (tid == 0) offs[D] = part[256];
}

__global__ void k_fill(const int* __restrict__ row, const int* __restrict__ offs,
                       int* __restrict__ cursor, int* __restrict__ list, int F, int Dn)
{
    int f = blockIdx.x*blockDim.x + threadIdx.x;
    if (f >= F) return;
    int r = clampi(row[f],0,Dn-1);
    int p = atomicAdd(&cursor[r], 1);
    int pos = offs[r]+p;
    if (pos >= 0 && pos < F) list[pos] = f;
}

__global__ void k_build_inv(const int* __restrict__ fs, const int* __restrict__ fp,
                            int* __restrict__ inv, int F, int L, int S)
{
    int f = blockIdx.x*blockDim.x + threadIdx.x;
    if (f >= F) return;
    inv[clampi(fs[f],0,S-1)*L + clampi(fp[f],0,L-1)] = f;
}

__global__ void k_pool_add(const float* __restrict__ frag, const int* __restrict__ fs,
                           float* __restrict__ pooled, int F, int S)
{
    int t = blockIdx.x*blockDim.x + threadIdx.x;
    int i = t >> 7, j = t & 127;
    if (i >= F) return;
    atomicAdd(&pooled[(size_t)clampi(fs[i],0,S-1)*128 + j], frag[(size_t)i*128 + j]);
}

__global__ void k_pool_div(float* __restrict__ pooled, const int* __restrict__ lengths, int S)
{
    int t = blockIdx.x*blockDim.x + threadIdx.x;
    int i = t >> 7, j = t & 127;
    if (i >= S) return;
    int l = lengths[i]; if (l < 1) l = 1;
    pooled[(size_t)i*128 + j] /= (float)l;
}

__global__ void k_dot_out(const float* __restrict__ H, const float* __restrict__ W3,
                          const float* __restrict__ b3, float* __restrict__ outv, int off)
{
    __shared__ float red[256];
    int s = blockIdx.x, tid = threadIdx.x;
    red[tid] = H[(size_t)s*256 + tid] * W3[tid];
    __syncthreads();
    for (int st=128; st; st>>=1){ if (tid < st) red[tid] += red[tid+st]; __syncthreads(); }
    if (tid == 0) outv[off + s] = red[0] + b3[0];
}

// =====================================================================================
extern "C" void kernel_launch(void* const* d_in, const int* in_sizes, int n_in,
                              void* d_out, int out_size, void* d_ws, size_t ws_size,
                              hipStream_t stream)
{
    (void)n_in; (void)out_size; (void)ws_size;
    const float* realnode = (const float*)d_in[0];
    const float* arr      = (const float*)d_in[1];
    const int* r_exe   = (const int*)d_in[2];
    const int* r_idev  = (const int*)d_in[3];
    const int* r_ifrag = (const int*)d_in[4];
    const int* r_fdn   = (const int*)d_in[5];
    const int* r_fdr   = (const int*)d_in[6];
    const int* r_len   = (const int*)d_in[7];
    const int* r_fsvc  = (const int*)d_in[8];
    const int* r_fpos  = (const int*)d_in[9];
    const float *W_dev=(const float*)d_in[10], *b_dev=(const float*)d_in[11];
    const float *W_frg=(const float*)d_in[12], *b_frg=(const float*)d_in[13];
    const float *W_srv=(const float*)d_in[14], *b_srv=(const float*)d_in[15];
    const float *C_Wih=(const float*)d_in[16], *C_Whh=(const float*)d_in[17], *C_bih=(const float*)d_in[18], *C_bhh=(const float*)d_in[19];
    const float *F_Wih=(const float*)d_in[20], *F_Whh=(const float*)d_in[21], *F_bih=(const float*)d_in[22], *F_bhh=(const float*)d_in[23];
    const float *D_Wih=(const float*)d_in[24], *D_Whh=(const float*)d_in[25], *D_bih=(const float*)d_in[26], *D_bhh=(const float*)d_in[27];
    const float *W_src=(const float*)d_in[28], *b_src=(const float*)d_in[29];
    const float *W_tgt=(const float*)d_in[30], *b_tgt=(const float*)d_in[31];
    const float *att=(const float*)d_in[32], *bias_att=(const float*)d_in[33];
    const float *Wt1=(const float*)d_in[34], *bt1=(const float*)d_in[35], *Wt2=(const float*)d_in[36], *bt2=(const float*)d_in[37], *Wt3=(const float*)d_in[38], *bt3=(const float*)d_in[39];
    const float *Wl1=(const float*)d_in[40], *bl1=(const float*)d_in[41], *Wl2=(const float*)d_in[42], *bl2=(const float*)d_in[43], *Wl3=(const float*)d_in[44], *bl3=(const float*)d_in[45];
    float* outp = (float*)d_out;

    const int S  = in_sizes[7];
    const int Dn = in_sizes[3];
    const int F  = in_sizes[4];
    const int L  = in_sizes[2] / (2*S);
    const int nreal = in_sizes[0]/5;
    const int nodes = nreal + 1;
    const int NIT = 3;
    const int FH = F/2;

    char* wp = (char*)d_ws;
    auto alloc = [&](size_t nelem)->float*{
        float* p = (float*)wp;
        wp += ((nelem*4 + 255)/256)*256;
        return p;
    };
    float* state  = alloc((size_t)nodes*128);
    float* h_srv  = alloc((size_t)S*128);
    float* out_f  = alloc((size_t)F*128);
    float* fragA  = alloc((size_t)F*128);
    float* devA   = alloc((size_t)Dn*128);
    float* alphaB = alloc((size_t)F*4);
    float* msgDm  = alloc((size_t)Dn*256);
    float* saB    = alloc((size_t)Dn*4);
    float* giF    = alloc((size_t)F*384);
    float* TGT    = alloc((size_t)Dn*1024);
    float* Z      = alloc((size_t)Dn*1024);
    float* pooled = alloc((size_t)S*128);
    unsigned short* tCWih   = (unsigned short*)alloc(384*256/2);
    unsigned short* tCWhhHi = (unsigned short*)alloc(384*128/2);
    unsigned short* tCWhhLo = (unsigned short*)alloc(384*128/2);
    unsigned short* tFWih   = (unsigned short*)alloc(384*256/2);
    unsigned short* tFWhh   = (unsigned short*)alloc(384*128/2);
    unsigned short* tDWih   = (unsigned short*)alloc(384*256/2);
    unsigned short* tDWhh   = (unsigned short*)alloc(384*128/2);
    unsigned short* tWtgt   = (unsigned short*)alloc(1024*128/2);
    unsigned short* tWsrc   = (unsigned short*)alloc(1024*256/2);
    unsigned short* tWsrcC  = (unsigned short*)alloc(256*1024/2);
    int* cExe   = (int*)alloc((size_t)S*2*L);
    int* cIdev  = (int*)alloc((size_t)Dn);
    int* cIfrag = (int*)alloc((size_t)F);
    int* cFdn   = (int*)alloc((size_t)F);
    int* cFdr   = (int*)alloc((size_t)F);
    int* cLen   = (int*)alloc((size_t)S);
    int* cFsvc  = (int*)alloc((size_t)F);
    int* cFpos  = (int*)alloc((size_t)F);
    int* inv    = (int*)alloc((size_t)S*L);
    int* counts = (int*)alloc((size_t)Dn);
    int* offs   = (int*)alloc((size_t)Dn+1);
    int* cursor = (int*)alloc((size_t)Dn);
    int* list   = (int*)alloc((size_t)F);

    const int* det = r_idev;
    auto cvt = [&](const int* src, int* dst, int n){
        k_cvt<<<dim3((n+255)/256),256,0,stream>>>(src, dst, n, det);
    };
    cvt(r_exe,  cExe,  S*2*L);
    cvt(r_idev, cIdev, Dn);
    cvt(r_ifrag,cIfrag,F);
    cvt(r_fdn,  cFdn,  F);
    cvt(r_fdr,  cFdr,  F);
    cvt(r_len,  cLen,  S);
    cvt(r_fsvc, cFsvc, F);
    cvt(r_fpos, cFpos, F);

    k_wt<<<dim3((98304+255)/256),256,0,stream>>>(C_Wih, tCWih, 384, 8, 255, 98304);
    k_wt2<<<dim3((49152+255)/256),256,0,stream>>>(C_Whh, tCWhhHi, tCWhhLo, 384, 7, 127, 49152);
    k_wt<<<dim3((98304+255)/256),256,0,stream>>>(F_Wih, tFWih, 384, 8, 255, 98304);
    k_wt<<<dim3((49152+255)/256),256,0,stream>>>(F_Whh, tFWhh, 384, 7, 127, 49152);
    k_wt<<<dim3((98304+255)/256),256,0,stream>>>(D_Wih, tDWih, 384, 8, 255, 98304);
    k_wt<<<dim3((49152+255)/256),256,0,stream>>>(D_Whh, tDWhh, 384, 7, 127, 49152);
    k_wt<<<dim3((131072+255)/256),256,0,stream>>>(W_tgt, tWtgt, 1024, 7, 127, 131072);
    k_wt<<<dim3((262144+255)/256),256,0,stream>>>(W_src, tWsrc, 1024, 8, 255, 262144);
    k_wtc<<<dim3((262144+255)/256),256,0,stream>>>(W_src, tWsrcC, 262144);

    hipMemsetAsync(state, 0, (size_t)nodes*128*4, stream);
    hipMemsetAsync(inv, 0xFF, (size_t)S*L*4, stream);
    hipMemsetAsync(counts, 0, (size_t)Dn*4, stream);
    hipMemsetAsync(cursor, 0, (size_t)Dn*4, stream);

    k_proj5<<<dim3((Dn*128+255)/256),256,0,stream>>>(realnode, W_dev, b_dev, cIdev, cIdev, state, devA, Dn, nreal, nodes);
    k_proj5<<<dim3(((size_t)F*128+255)/256),256,0,stream>>>(realnode, W_frg, b_frg, cIfrag, cIfrag, state, fragA, F, nreal, nodes);
    k_proj5<<<dim3((S*128+255)/256),256,0,stream>>>(arr, W_srv, b_srv, nullptr, nullptr, h_srv, nullptr, S, S, nodes);
    k_build_inv<<<dim3((F+255)/256),256,0,stream>>>(cFsvc, cFpos, inv, F, L, S);
    k_count<<<dim3((F+255)/256),256,0,stream>>>(cFdr, counts, F, Dn);
    k_scan<<<1,256,0,stream>>>(counts, offs, Dn);
    k_fill<<<dim3((F+255)/256),256,0,stream>>>(cFdr, offs, cursor, list, F, Dn);

    for (int it=0; it<NIT; ++it){
        // phiC: batched gi (MFMA) + fused MFMA recurrence
        mm_bf<<<dim3(3, F/128),256,0,stream>>>(state, state, cIfrag, cFdn, 0,
            tCWih, C_bih, giF, F, 384, 256, 0, 1.f, nullptr, nullptr, nullptr, nullptr, nullptr);
        k_recur<<<dim3(S/16),512,0,stream>>>(h_srv, giF, tCWhhHi, tCWhhLo, C_bhh, inv, out_f, S, L, F);
        // attention
        mm_bf<<<dim3(8, Dn/128),256,0,stream>>>(devA, nullptr, nullptr, nullptr, 128,
            tWtgt, b_tgt, TGT, Dn, 1024, 128, 0, 1.f, nullptr, nullptr, nullptr, nullptr, nullptr);
        hipMemsetAsync(alphaB, 0, (size_t)F*4*4, stream);
        mm_bf<<<dim3(8, F/128),256,0,stream>>>(out_f, fragA, nullptr, nullptr, 0,
            tWsrc, nullptr, nullptr, F, 1024, 256, 1, 1.f, TGT, cFdr, att, b_src, alphaB);
        k_attn_z<<<dim3(Dn),256,0,stream>>>(out_f, fragA, alphaB, list, offs, Z, saB, Dn, F);
        mm_bf<<<dim3(2, Dn/128),256,0,stream>>>(Z, nullptr, nullptr, nullptr, 1024,
            tWsrcC, nullptr, msgDm, Dn, 256, 1024, 0, 0.25f, nullptr, nullptr, nullptr, nullptr, nullptr);
        k_msgd_fix<<<dim3((Dn*256+255)/256),256,0,stream>>>(msgDm, saB, b_src, bias_att, Dn);
        // F-GRU chunked 2x (in-place, write-through to state)
        for (int c=0;c<2;c++){
            size_t off = (size_t)c*FH;
            mm_bf<<<dim3(3, FH/128),256,0,stream>>>(out_f + off*128, state, nullptr, cFdn + off, 0,
                tFWih, F_bih, TGT, FH, 384, 256, 0, 1.f, nullptr, nullptr, nullptr, nullptr, nullptr);
            mm_bf<<<dim3(3, FH/128),256,0,stream>>>(fragA + off*128, nullptr, nullptr, nullptr, 128,
                tFWhh, F_bhh, Z, FH, 384, 128, 0, 1.f, nullptr, nullptr, nullptr, nullptr, nullptr);
            k_gru<<<dim3(((size_t)FH*128+255)/256),256,0,stream>>>(TGT, Z, fragA + off*128, fragA + off*128,
                state, cIfrag + off, FH, nodes);
        }
        // D-GRU (in-place, write-through to state)
        mm_bf<<<dim3(3, Dn/128),256,0,stream>>>(msgDm, nullptr, nullptr, nullptr, 256,
            tDWih, D_bih, TGT, Dn, 384, 256, 0, 1.f, nullptr, nullptr, nullptr, nullptr, nullptr);
        mm_bf<<<dim3(3, Dn/128),256,0,stream>>>(devA, nullptr, nullptr, nullptr, 128,
            tDWhh, D_bhh, Z, Dn, 384, 128, 0, 1.f, nullptr, nullptr, nullptr, nullptr, nullptr);
        k_gru<<<dim3((Dn*128+255)/256),256,0,stream>>>(TGT, Z, devA, devA, state, cIdev, Dn, nodes);
    }

    // readout
    hipMemsetAsync(pooled, 0, (size_t)S*128*4, stream);
    k_pool_add<<<dim3(((size_t)F*128+255)/256),256,0,stream>>>(fragA, cFsvc, pooled, F, S);
    k_pool_div<<<dim3((S*128+255)/256),256,0,stream>>>(pooled, cLen, S);
    k_mm<<<dim3(256/128, S/128),256,0,stream>>>(pooled, 128, Wl1, 256, bl1, TGT, S, 256, 128, 1, 1.f, 0);
    k_mm<<<dim3(256/128, S/128),256,0,stream>>>(TGT, 256, Wl2, 256, bl2, Z, S, 256, 256, 1, 1.f, 0);
    k_dot_out<<<dim3(S),256,0,stream>>>(Z, Wl3, bl3, outp, 0);
    k_mm<<<dim3(256/128, S/128),256,0,stream>>>(h_srv, 128, Wt1, 256, bt1, TGT, S, 256, 128, 1, 1.f, 0);
    k_mm<<<dim3(256/128, S/128),256,0,stream>>>(TGT, 256, Wt2, 256, bt2, Z, S, 256, 256, 1, 1.f, 0);
    k_dot_out<<<dim3(S),256,0,stream>>>(Z, Wt3, bt3, outp, S);
}